// Round 16
// baseline (633.927 us; speedup 1.0000x reference)
//
#include <hip/hip_runtime.h>
#include <cstdint>
#include <cstddef>

#define MB    8192
#define NSAE  16384
#define KIN   768
#define KSEL  32
#define NBIN  1024
#define BAND  8      // +/- band (bf16 ULP bins) around screened rank-32
#define UMAX  160    // uncertain-candidate capacity (typ ~25)
#define CMAX  40     // certain-in capacity (provably <= 31)
#define NCMAX 128    // legacy fallback kernels

#define BM  128
#define BN  128
#define BKK 16
#define APAD 132

typedef __attribute__((ext_vector_type(8))) short bfrag;
typedef __attribute__((ext_vector_type(4))) float ffrag;

__device__ __forceinline__ unsigned short f2bf(float f) {
    unsigned u = __float_as_uint(f);
    return (unsigned short)((u + 0x7FFFu + ((u >> 16) & 1u)) >> 16);
}

__device__ __forceinline__ void async_load16(const void* gsrc, void* ldsdst) {
    __builtin_amdgcn_global_load_lds(
        (const __attribute__((address_space(1))) unsigned int*)gsrc,
        (__attribute__((address_space(3))) unsigned int*)ldsdst,
        16, 0, 0);
}

// ---------------------------------------------------------------------------
// Prep A: Aws[m][k ^ ((m&7)*8)] = bf16(x[m][k] - bdec[k])   (swizzled bf16)
// ---------------------------------------------------------------------------
__global__ __launch_bounds__(256) void conv_x(
    const float* __restrict__ x, const float* __restrict__ bdec,
    unsigned short* __restrict__ Aws)
{
    const int t  = blockIdx.x * 256 + threadIdx.x;
    const int m  = t / (KIN / 8);
    const int k0 = (t % (KIN / 8)) * 8;
    const float4 v0 = *reinterpret_cast<const float4*>(&x[(size_t)m * KIN + k0]);
    const float4 v1 = *reinterpret_cast<const float4*>(&x[(size_t)m * KIN + k0 + 4]);
    const float4 b0 = *reinterpret_cast<const float4*>(&bdec[k0]);
    const float4 b1 = *reinterpret_cast<const float4*>(&bdec[k0 + 4]);
    uint4 o;
    o.x = (unsigned)f2bf(v0.x - b0.x) | ((unsigned)f2bf(v0.y - b0.y) << 16);
    o.y = (unsigned)f2bf(v0.z - b0.z) | ((unsigned)f2bf(v0.w - b0.w) << 16);
    o.z = (unsigned)f2bf(v1.x - b1.x) | ((unsigned)f2bf(v1.y - b1.y) << 16);
    o.w = (unsigned)f2bf(v1.z - b1.z) | ((unsigned)f2bf(v1.w - b1.w) << 16);
    *reinterpret_cast<uint4*>(&Aws[(size_t)m * KIN + (k0 ^ ((m & 7) * 8))]) = o;
}

// ---------------------------------------------------------------------------
// Prep B: WT[n][k] = W_enc[k][n] (fp32) and optionally swizzled bf16 Bws
// ---------------------------------------------------------------------------
__global__ __launch_bounds__(256) void transpose_wenc(
    const float* __restrict__ W, float* __restrict__ WT,
    unsigned short* __restrict__ Bws)
{
    __shared__ float t[32][33];
    const int bn = blockIdx.x * 32;
    const int bk = blockIdx.y * 32;
    const int lx = threadIdx.x & 31;
    const int ly = threadIdx.x >> 5;
#pragma unroll
    for (int r = 0; r < 4; ++r)
        t[ly + 8 * r][lx] = W[(size_t)(bk + ly + 8 * r) * NSAE + bn + lx];
    __syncthreads();
#pragma unroll
    for (int r = 0; r < 4; ++r) {
        const int n = bn + ly + 8 * r;
        const int k = bk + lx;
        const float v = t[lx][ly + 8 * r];
        WT[(size_t)n * KIN + k] = v;
        if (Bws) Bws[(size_t)n * KIN + (k ^ ((n & 7) * 8))] = f2bf(v);
    }
}

// ---------------------------------------------------------------------------
// Prep C: WdB = bf16(W_dec), same [NSAE][KIN] layout (halves decode traffic)
// ---------------------------------------------------------------------------
__global__ __launch_bounds__(256) void conv_wdec(
    const float* __restrict__ W, unsigned short* __restrict__ WB)
{
    const size_t t = (size_t)blockIdx.x * 256 + threadIdx.x;  // NSAE*KIN/8
    const float4 v0 = *reinterpret_cast<const float4*>(&W[t * 8]);
    const float4 v1 = *reinterpret_cast<const float4*>(&W[t * 8 + 4]);
    uint4 o;
    o.x = (unsigned)f2bf(v0.x) | ((unsigned)f2bf(v0.y) << 16);
    o.y = (unsigned)f2bf(v0.z) | ((unsigned)f2bf(v0.w) << 16);
    o.z = (unsigned)f2bf(v1.x) | ((unsigned)f2bf(v1.y) << 16);
    o.w = (unsigned)f2bf(v1.z) | ((unsigned)f2bf(v1.w) << 16);
    *reinterpret_cast<uint4*>(&WB[t * 8]) = o;
}

// ---------------------------------------------------------------------------
// Kernel 1: bf16 MFMA screening GEMM -> bf16 pre (row-strided into z region)
// 256x128 block tile, 8 waves (4 row x 2 col).
// NEW: epilogue also zeroes this block's 64-fp32-col slice of the SECOND
// half of each covered z row (fused kernel then only zeroes the first half).
// ---------------------------------------------------------------------------
__global__ __launch_bounds__(512) void sae_encode_mfma(
    const unsigned short* __restrict__ Aws,
    const unsigned short* __restrict__ Bws,
    const float* __restrict__ benc,
    unsigned short* __restrict__ preB,   // == (ushort*)z base
    int rstride)                         // row stride in ushorts (= NSAE*2)
{
    __shared__ __align__(16) unsigned short Al[256 * 64];   // 32 KB
    __shared__ __align__(16) unsigned short Bl[128 * 64];   // 16 KB

    const int tid = threadIdx.x;
    const int w   = tid >> 6;            // 0..7
    const int l   = tid & 63;
    const int wr  = (w >> 1) * 64;       // 0,64,128,192
    const int wc  = (w & 1) * 64;        // 0,64
    const int row0 = blockIdx.y * 256;
    const int col0 = blockIdx.x * 128;

    ffrag acc[4][4];
#pragma unroll
    for (int i = 0; i < 4; ++i)
#pragma unroll
        for (int j = 0; j < 4; ++j)
#pragma unroll
            for (int r = 0; r < 4; ++r) acc[i][j][r] = 0.0f;

    const int sra = w * 32 + (l >> 3);
    const int srb = w * 16 + (l >> 3);
    const int sb  = (l & 7) * 16;
    const char* Ag = (const char*)(Aws + (size_t)(row0 + sra) * KIN) + sb;
    const char* Bg = (const char*)(Bws + (size_t)(col0 + srb) * KIN) + sb;

    const int g = l >> 4;
    const int q = l & 15;

    for (int kt = 0; kt < KIN / 64; ++kt) {
#pragma unroll
        for (int i = 0; i < 4; ++i)
            async_load16(Ag + (size_t)i * 8 * (KIN * 2) + kt * 128,
                         &Al[(w * 32 + i * 8) * 64]);
#pragma unroll
        for (int i = 0; i < 2; ++i)
            async_load16(Bg + (size_t)i * 8 * (KIN * 2) + kt * 128,
                         &Bl[(w * 16 + i * 8) * 64]);
        __syncthreads();
#pragma unroll
        for (int kk = 0; kk < 2; ++kk) {
            bfrag af[4], bf[4];
#pragma unroll
            for (int mf = 0; mf < 4; ++mf) {
                const int m = wr + mf * 16 + q;
                af[mf] = *reinterpret_cast<const bfrag*>(
                    &Al[m * 64 + ((kk * 32 + g * 8) ^ ((m & 7) * 8))]);
            }
#pragma unroll
            for (int nf = 0; nf < 4; ++nf) {
                const int n = wc + nf * 16 + q;
                bf[nf] = *reinterpret_cast<const bfrag*>(
                    &Bl[n * 64 + ((kk * 32 + g * 8) ^ ((n & 7) * 8))]);
            }
#pragma unroll
            for (int mf = 0; mf < 4; ++mf)
#pragma unroll
                for (int nf = 0; nf < 4; ++nf)
                    acc[mf][nf] = __builtin_amdgcn_mfma_f32_16x16x32_bf16(
                        af[mf], bf[nf], acc[mf][nf], 0, 0, 0);
        }
        __syncthreads();
    }

    // epilogue: + b_enc, relu, store bf16 (row stride = rstride ushorts)
#pragma unroll
    for (int nf = 0; nf < 4; ++nf) {
        const int gc = col0 + wc + nf * 16 + q;
        const float be = benc[gc];
#pragma unroll
        for (int mf = 0; mf < 4; ++mf) {
            const int gr = row0 + wr + mf * 16 + g * 4;
#pragma unroll
            for (int r = 0; r < 4; ++r)
                preB[(size_t)(gr + r) * rstride + gc] =
                    f2bf(fmaxf(acc[mf][nf][r] + be, 0.0f));
        }
    }

    // NEW: zero this block's slice of the z second half.
    // z row r (fp32) = preB base + r * NSAE floats; second half = cols
    // [8192, 16384). This block owns 64 cols at 8192 + col0/2 for its
    // 256 rows: 256 rows x 64 floats = 4096 float4 / 512 threads = 8 each.
    {
        float* zs = (float*)preB;
        const int zc = 8192 + (col0 >> 1);
        const float4 z4 = make_float4(0.0f, 0.0f, 0.0f, 0.0f);
#pragma unroll
        for (int i = 0; i < 8; ++i) {
            const int idx = i * 512 + tid;      // 0..4095
            const int r   = idx >> 4;           // 0..255
            const int c   = (idx & 15) * 4;     // 0..60
            *reinterpret_cast<float4*>(
                &zs[(size_t)(row0 + r) * NSAE + zc + c]) = z4;
        }
    }
}

// ---------------------------------------------------------------------------
// Kernel 2: fused select+decode with certainty-band refinement.
// Zeroes only the FIRST half of the z row (second half zeroed by encode).
// ---------------------------------------------------------------------------
__global__ __launch_bounds__(256) void sae_fused(
    const float* __restrict__ x,
    const float* __restrict__ WT,        // [NSAE][KIN] fp32
    const float* __restrict__ benc,
    const float* __restrict__ bdec,
    const unsigned short* __restrict__ WdB,  // [NSAE][KIN] bf16
    float* __restrict__ xhat,            // [MB][KIN]
    float* __restrict__ z)               // [MB][NSAE]; first 32KB of row = preB
{
    const int row = blockIdx.x;
    const int tid = threadIdx.x;
    float* rp = z + (size_t)row * NSAE;
    const unsigned short* pp = (const unsigned short*)rp;

    __shared__ int      hist[NBIN];
    __shared__ int      s_v32;
    __shared__ int      s_cc;
    __shared__ int      s_uc;
    __shared__ int      cidx[CMAX];
    __shared__ float    cval[CMAX];
    __shared__ int      uidx[UMAX];
    __shared__ float    ukey[UMAX];
    __shared__ double   xsd[KIN];
    __shared__ float    selv[KSEL];
    __shared__ int      selp[KSEL];

    // ---- stage this row's bf16 pre into registers ----
    uint4 u4[8];
#pragma unroll
    for (int i = 0; i < 8; ++i)
        u4[i] = reinterpret_cast<const uint4*>(pp)[i * 256 + tid];

    for (int i = tid; i < NBIN; i += 256) hist[i] = 0;
    if (tid == 0) { s_cc = 0; s_uc = 0; s_v32 = -1; }
    if (tid < KSEL) { selv[tid] = 0.0f; selp[tid] = 0; }
    for (int i = tid; i < KIN; i += 256)
        xsd[i] = (double)x[(size_t)row * KIN + i] - (double)bdec[i];
    __syncthreads();

    // ---- exact bf16-resolution histogram of values >= 1.0 (0x3F80) ----
#pragma unroll
    for (int i = 0; i < 8; ++i) {
        const unsigned wv[4] = {u4[i].x, u4[i].y, u4[i].z, u4[i].w};
#pragma unroll
        for (int j = 0; j < 4; ++j) {
            const unsigned lo = wv[j] & 0xFFFFu;
            const unsigned hi = wv[j] >> 16;
            if (lo >= 0x3F80u) {
                int b = (int)(lo - 0x3F80u); if (b > NBIN - 1) b = NBIN - 1;
                atomicAdd(&hist[b], 1);
            }
            if (hi >= 0x3F80u) {
                int b = (int)(hi - 0x3F80u); if (b > NBIN - 1) b = NBIN - 1;
                atomicAdd(&hist[b], 1);
            }
        }
    }

    // ---- zero FIRST half of z row (bytes we just read; second half was
    //      zeroed by the encode kernel's epilogue) ----
    const float4 z4 = make_float4(0.0f, 0.0f, 0.0f, 0.0f);
#pragma unroll
    for (int i = 0; i < 8; ++i)
        reinterpret_cast<float4*>(rp)[i * 256 + tid] = z4;
    __syncthreads();

    // ---- wave 0: suffix-scan 1024 bins -> screened rank-32 bin ----
    if (tid < 64) {
        int hb[16]; int s16 = 0;
#pragma unroll
        for (int b = 0; b < 16; ++b) { hb[b] = hist[tid * 16 + b]; s16 += hb[b]; }
        int suf = s16;
#pragma unroll
        for (int off = 1; off < 64; off <<= 1) {
            const int v = __shfl_down(suf, off);
            if (tid + off < 64) suf += v;
        }
        const int tail  = suf - s16;
        const int total = __shfl(suf, 0);
        if (total >= KSEL && tail < KSEL && suf >= KSEL) {
            int cum = tail;
#pragma unroll
            for (int b = 15; b >= 0; --b) {
                cum += hb[b];
                if (cum >= KSEL) { s_v32 = tid * 16 + b; break; }
            }
        }
    }
    __syncthreads();

    const int v32 = s_v32;
    unsigned Tlo, Thi;
    if (v32 >= 3 * BAND) {
        Tlo = 0x3F80u + (unsigned)(v32 - BAND);
        Thi = 0x3F80u + (unsigned)(v32 + BAND);
    } else {
        Tlo = 0x3F80u;
        Thi = 0xFFFFu;
    }

    // ---- collect certain-in and uncertain candidates ----
#pragma unroll
    for (int i = 0; i < 8; ++i) {
        const unsigned wv[4] = {u4[i].x, u4[i].y, u4[i].z, u4[i].w};
#pragma unroll
        for (int j = 0; j < 4; ++j) {
            const int base = (i * 256 + tid) * 8 + j * 2;
            const unsigned bb[2] = {wv[j] & 0xFFFFu, wv[j] >> 16};
#pragma unroll
            for (int h = 0; h < 2; ++h) {
                const unsigned b = bb[h];
                if (b > Thi) {
                    const int s = atomicAdd(&s_cc, 1);
                    if (s < CMAX) {
                        cidx[s] = base + h;
                        cval[s] = __uint_as_float(b << 16);
                    }
                } else if (b >= Tlo) {
                    const int s = atomicAdd(&s_uc, 1);
                    if (s < UMAX) uidx[s] = base + h;
                }
            }
        }
    }
    __syncthreads();
    const int C = (s_cc < KSEL) ? s_cc : KSEL;
    const int U = (s_uc < UMAX) ? s_uc : UMAX;
    const int need = KSEL - C;

    // ---- fp64 refinement of uncertain -> fp32 keys (R12 scalar form) ----
    for (int cnd = tid >> 2; cnd < U; cnd += 64) {
        const int lane = tid & 3;
        const int idx  = uidx[cnd];
        const float* wp = WT + (size_t)idx * KIN + lane;
        double acc = 0.0;
        for (int j = 0; j < KIN / 4; ++j)
            acc = fma(xsd[lane + j * 4], (double)wp[j * 4], acc);
        acc += __shfl_down(acc, 2, 4);
        acc += __shfl_down(acc, 1, 4);
        if (lane == 0)
            ukey[cnd] = fmaxf((float)(acc + (double)benc[idx]), 0.0f);
    }
    __syncthreads();

    // ---- fill selection: certains first, then top-need uncertain ----
    if (tid < C) { selv[tid] = cval[tid]; selp[tid] = cidx[tid]; }
    if (tid < U) {
        const float v = ukey[tid];
        const int   p = uidx[tid];
        int rank = 0;
        for (int j = 0; j < U; ++j) {
            const float vj = ukey[j];
            const int   pj = uidx[j];
            if (vj > v || (vj == v && pj < p)) ++rank;
        }
        if (rank < need) { selv[C + rank] = v; selp[C + rank] = p; }
    }
    __syncthreads();   // drains the first-half zero stores block-wide too

    // ---- scatter selection into the zeroed z row ----
    if (tid < KSEL && selv[tid] != 0.0f) rp[selp[tid]] = selv[tid];

    // ---- sparse decode from bf16 Wdec: xhat = b_dec + sum_j v_j*Wdec[p_j] ----
    const unsigned* Wd32 = (const unsigned*)WdB;   // [NSAE][KIN/2] packed pairs
#pragma unroll
    for (int pass = 0; pass < 2; ++pass) {
        const int u = tid + pass * 256;            // column pair index
        if (u < KIN / 2) {
            float a0 = bdec[2 * u];
            float a1 = bdec[2 * u + 1];
#pragma unroll 8
            for (int j = 0; j < KSEL; ++j) {
                const unsigned w = Wd32[(size_t)selp[j] * (KIN / 2) + u];
                a0 = fmaf(selv[j], __uint_as_float(w << 16), a0);
                a1 = fmaf(selv[j], __uint_as_float(w & 0xFFFF0000u), a1);
            }
            float2 o; o.x = a0; o.y = a1;
            *reinterpret_cast<float2*>(&xhat[(size_t)row * KIN + 2 * u]) = o;
        }
    }
}

// ---------------------------------------------------------------------------
// Fallback kernels (fp32 pipeline, used only when workspace is small)
// ---------------------------------------------------------------------------
__global__ __launch_bounds__(256) void sae_encode_gemm(
    const float* __restrict__ x,
    const float* __restrict__ Wenc,
    const float* __restrict__ benc,
    const float* __restrict__ bdec,
    float* __restrict__ pre)
{
    __shared__ float As[BKK][APAD];
    __shared__ float Bs[BKK][BN];

    const int tid  = threadIdx.x;
    const int tx   = tid & 15;
    const int ty   = tid >> 4;
    const int col0 = blockIdx.x * BN;
    const int row0 = blockIdx.y * BM;

    const int ar = tid >> 2;
    const int ac = (tid & 3) << 2;
    const int br = tid >> 5;
    const int bc = (tid & 31) << 2;

    float acc[8][8];
#pragma unroll
    for (int i = 0; i < 8; ++i)
#pragma unroll
        for (int j = 0; j < 8; ++j) acc[i][j] = 0.0f;

    for (int kt = 0; kt < KIN; kt += BKK) {
        const float bd0 = bdec[kt + ac + 0];
        const float bd1 = bdec[kt + ac + 1];
        const float bd2 = bdec[kt + ac + 2];
        const float bd3 = bdec[kt + ac + 3];
#pragma unroll
        for (int h = 0; h < 2; ++h) {
            const int r = ar + h * 64;
            const float4 av = *reinterpret_cast<const float4*>(
                &x[(size_t)(row0 + r) * KIN + kt + ac]);
            As[ac + 0][r] = av.x - bd0;
            As[ac + 1][r] = av.y - bd1;
            As[ac + 2][r] = av.z - bd2;
            As[ac + 3][r] = av.w - bd3;
        }
#pragma unroll
        for (int h = 0; h < 2; ++h) {
            const int r = br + h * 8;
            *reinterpret_cast<float4*>(&Bs[r][bc]) =
                *reinterpret_cast<const float4*>(
                    &Wenc[(size_t)(kt + r) * NSAE + col0 + bc]);
        }
        __syncthreads();

#pragma unroll
        for (int k = 0; k < BKK; ++k) {
            float a[8], b[8];
            *reinterpret_cast<float4*>(&a[0]) =
                *reinterpret_cast<const float4*>(&As[k][ty * 4]);
            *reinterpret_cast<float4*>(&a[4]) =
                *reinterpret_cast<const float4*>(&As[k][64 + ty * 4]);
            *reinterpret_cast<float4*>(&b[0]) =
                *reinterpret_cast<const float4*>(&Bs[k][tx * 4]);
            *reinterpret_cast<float4*>(&b[4]) =
                *reinterpret_cast<const float4*>(&Bs[k][64 + tx * 4]);
#pragma unroll
            for (int i = 0; i < 8; ++i)
#pragma unroll
                for (int j = 0; j < 8; ++j)
                    acc[i][j] = fmaf(a[i], b[j], acc[i][j]);
        }
        __syncthreads();
    }

#pragma unroll
    for (int i = 0; i < 8; ++i) {
        const int gr = row0 + ((i & 3) + ty * 4) + ((i >> 2) * 64);
#pragma unroll
        for (int jg = 0; jg < 2; ++jg) {
            const int gc = col0 + tx * 4 + jg * 64;
            float4 v;
            v.x = fmaxf(acc[i][jg * 4 + 0] + benc[gc + 0], 0.0f);
            v.y = fmaxf(acc[i][jg * 4 + 1] + benc[gc + 1], 0.0f);
            v.z = fmaxf(acc[i][jg * 4 + 2] + benc[gc + 2], 0.0f);
            v.w = fmaxf(acc[i][jg * 4 + 3] + benc[gc + 3], 0.0f);
            *reinterpret_cast<float4*>(&pre[(size_t)gr * NSAE + gc]) = v;
        }
    }
}

template <bool TR>
__global__ __launch_bounds__(256) void sae_topk_decode(
    float* __restrict__ z,
    const float* __restrict__ x,
    const float* __restrict__ Wcol,
    const float* __restrict__ benc,
    const float* __restrict__ Wdec,
    const float* __restrict__ bdec,
    float* __restrict__ xhat)
{
    const int row = blockIdx.x;
    const int tid = threadIdx.x;
    float* rp = z + (size_t)row * NSAE;

    __shared__ int      hist[16];
    __shared__ unsigned s_pfx;
    __shared__ int      s_need;
    __shared__ int      s_nc;
    __shared__ int      candp[NCMAX];
    __shared__ float    candf[NCMAX];
    __shared__ double   xsd[KIN];
    __shared__ float    selv[KSEL];
    __shared__ int      selp[KSEL];

    uint4 e[16];
#pragma unroll
    for (int i = 0; i < 16; ++i)
        e[i] = *reinterpret_cast<const uint4*>(&rp[i * 1024 + tid * 4]);

    if (tid == 0) { s_pfx = 0u; s_need = 64; s_nc = 0; }
    if (tid < 16) hist[tid] = 0;
    __syncthreads();

    for (int shift = 28; shift >= 0; shift -= 4) {
        const unsigned pfx   = s_pfx;
        const unsigned maskd = (shift == 28) ? 0u : (0xFFFFFFFFu << (shift + 4));
        int cnt[16];
#pragma unroll
        for (int d = 0; d < 16; ++d) cnt[d] = 0;
#pragma unroll
        for (int i = 0; i < 16; ++i) {
            const unsigned uu[4] = {e[i].x, e[i].y, e[i].z, e[i].w};
#pragma unroll
            for (int j = 0; j < 4; ++j)
                if ((uu[j] & maskd) == pfx) ++cnt[(uu[j] >> shift) & 15];
        }
#pragma unroll
        for (int d = 0; d < 16; ++d)
            if (cnt[d]) atomicAdd(&hist[d], cnt[d]);
        __syncthreads();
        if (tid == 0) {
            int cum = 0, sel = 0;
            const int need = s_need;
            for (int d = 15; d >= 0; --d) {
                const int c = hist[d];
                cum += c;
                if (cum >= need) { sel = d; s_need = need - (cum - c); break; }
            }
            s_pfx = pfx | ((unsigned)sel << shift);
        }
        __syncthreads();
        if (tid < 16) hist[tid] = 0;
        __syncthreads();
    }
    const unsigned T = s_pfx;

#pragma unroll
    for (int i = 0; i < 16; ++i) {
        const unsigned uu[4] = {e[i].x, e[i].y, e[i].z, e[i].w};
#pragma unroll
        for (int j = 0; j < 4; ++j) {
            if (uu[j] >= T) {
                const int slot = atomicAdd(&s_nc, 1);
                if (slot < NCMAX) candp[slot] = i * 1024 + tid * 4 + j;
            }
        }
    }
    if (tid < NCMAX) candf[tid] = -1.0f;
    for (int i = tid; i < KIN; i += 256)
        xsd[i] = (double)x[(size_t)row * KIN + i] - (double)bdec[i];
    __syncthreads();
    const int nc = (s_nc < NCMAX) ? s_nc : NCMAX;

    for (int cnd = tid >> 2; cnd < nc; cnd += 64) {
        const int lane = tid & 3;
        const int idx  = candp[cnd];
        double acc = 0.0;
        if (TR) {
            const float* wp = Wcol + (size_t)idx * KIN + lane;
            for (int j = 0; j < KIN / 4; ++j)
                acc = fma(xsd[lane + j * 4], (double)wp[j * 4], acc);
        } else {
            const float* wp = Wcol + idx;
            for (int j = 0; j < KIN / 4; ++j)
                acc = fma(xsd[lane + j * 4],
                          (double)wp[(size_t)(lane + j * 4) * NSAE], acc);
        }
        acc += __shfl_down(acc, 2, 4);
        acc += __shfl_down(acc, 1, 4);
        if (lane == 0)
            candf[cnd] = fmaxf((float)(acc + (double)benc[idx]), 0.0f);
    }
    __syncthreads();

    if (tid < KSEL) { selv[tid] = 0.0f; selp[tid] = 0; }
    __syncthreads();

    if (tid < nc) {
        const float v = candf[tid];
        const int   p = candp[tid];
        int rank = 0;
        for (int j = 0; j < nc; ++j) {
            const float vj = candf[j];
            const int   pj = candp[j];
            if (vj > v || (vj == v && pj < p)) ++rank;
        }
        if (rank < KSEL) { selv[rank] = v; selp[rank] = p; }
    }
    __syncthreads();

    const float4 zv4 = make_float4(0.0f, 0.0f, 0.0f, 0.0f);
#pragma unroll
    for (int i = 0; i < 16; ++i)
        *reinterpret_cast<float4*>(&rp[i * 1024 + tid * 4]) = zv4;
    __syncthreads();
    if (tid < KSEL && selv[tid] != 0.0f) rp[selp[tid]] = selv[tid];

#pragma unroll
    for (int t = 0; t < 3; ++t) {
        const int c = tid + t * 256;
        float accv = bdec[c];
#pragma unroll 8
        for (int j = 0; j < KSEL; ++j)
            accv = fmaf(selv[j], Wdec[(size_t)selp[j] * KIN + c], accv);
        xhat[(size_t)row * KIN + c] = accv;
    }
}

// ---------------------------------------------------------------------------
extern "C" void kernel_launch(void* const* d_in, const int* in_sizes, int n_in,
                              void* d_out, int out_size, void* d_ws, size_t ws_size,
                              hipStream_t stream) {
    const float* x    = (const float*)d_in[0];
    const float* Wenc = (const float*)d_in[1];
    const float* benc = (const float*)d_in[2];
    const float* Wdec = (const float*)d_in[3];
    const float* bdec = (const float*)d_in[4];

    float* xhat = (float*)d_out;                        // [8192, 768]
    float* z    = (float*)d_out + (size_t)MB * KIN;     // [8192, 16384]

    const size_t szA  = (size_t)MB * KIN * 2;           // 12.58 MB
    const size_t szB  = (size_t)NSAE * KIN * 2;         // 25.17 MB
    const size_t szWT = (size_t)NSAE * KIN * 4;         // 50.33 MB
    const size_t szWd = (size_t)NSAE * KIN * 2;         // 25.17 MB

    if (ws_size >= szA + szB + szWT + szWd) {
        unsigned short* Aws = (unsigned short*)d_ws;
        unsigned short* Bws = (unsigned short*)((char*)d_ws + szA);
        float*          WT  = (float*)((char*)d_ws + szA + szB);
        unsigned short* WdB = (unsigned short*)((char*)d_ws + szA + szB + szWT);
        unsigned short* preB = (unsigned short*)z;      // row-strided bf16 pre
        conv_x<<<dim3(MB * (KIN / 8) / 256), dim3(256), 0, stream>>>(x, bdec, Aws);
        transpose_wenc<<<dim3(NSAE / 32, KIN / 32), dim3(256), 0, stream>>>(Wenc, WT, Bws);
        conv_wdec<<<dim3((NSAE / 8) * (KIN / 256)), dim3(256), 0, stream>>>(Wdec, WdB);
        sae_encode_mfma<<<dim3(NSAE / 128, MB / 256), dim3(512), 0, stream>>>(
            Aws, Bws, benc, preB, NSAE * 2);
        sae_fused<<<dim3(MB), dim3(256), 0, stream>>>(
            x, WT, benc, bdec, WdB, xhat, z);
    } else if (ws_size >= szWT) {
        float* WT = (float*)d_ws;
        sae_encode_gemm<<<dim3(NSAE / BN, MB / BM), dim3(256), 0, stream>>>(
            x, Wenc, benc, bdec, z);
        transpose_wenc<<<dim3(NSAE / 32, KIN / 32), dim3(256), 0, stream>>>(Wenc, WT, nullptr);
        sae_topk_decode<true><<<dim3(MB), dim3(256), 0, stream>>>(
            z, x, WT, benc, Wdec, bdec, xhat);
    } else {
        sae_encode_gemm<<<dim3(NSAE / BN, MB / BM), dim3(256), 0, stream>>>(
            x, Wenc, benc, bdec, z);
        sae_topk_decode<false><<<dim3(MB), dim3(256), 0, stream>>>(
            z, x, Wenc, benc, Wdec, bdec, xhat);
    }
}

// Round 17
// 617.260 us; speedup vs baseline: 1.0270x; 1.0270x over previous
//
#include <hip/hip_runtime.h>
#include <cstdint>
#include <cstddef>

#define MB    8192
#define NSAE  16384
#define KIN   768
#define KSEL  32
#define NBIN  1024
#define BAND  8      // +/- band (bf16 ULP bins) around screened rank-32
#define UMAX  160    // uncertain-candidate capacity (typ ~25)
#define CMAX  40     // certain-in capacity (provably <= 31)
#define NCMAX 128    // legacy fallback kernels

#define BM  128
#define BN  128
#define BKK 16
#define APAD 132

typedef __attribute__((ext_vector_type(8))) short bfrag;
typedef __attribute__((ext_vector_type(4))) float ffrag;

__device__ __forceinline__ unsigned short f2bf(float f) {
    unsigned u = __float_as_uint(f);
    return (unsigned short)((u + 0x7FFFu + ((u >> 16) & 1u)) >> 16);
}

__device__ __forceinline__ void async_load16(const void* gsrc, void* ldsdst) {
    __builtin_amdgcn_global_load_lds(
        (const __attribute__((address_space(1))) unsigned int*)gsrc,
        (__attribute__((address_space(3))) unsigned int*)ldsdst,
        16, 0, 0);
}

// ---------------------------------------------------------------------------
// Prep A: Aws[m][k ^ ((m&7)*8)] = bf16(x[m][k] - bdec[k])   (swizzled bf16)
// ---------------------------------------------------------------------------
__global__ __launch_bounds__(256) void conv_x(
    const float* __restrict__ x, const float* __restrict__ bdec,
    unsigned short* __restrict__ Aws)
{
    const int t  = blockIdx.x * 256 + threadIdx.x;
    const int m  = t / (KIN / 8);
    const int k0 = (t % (KIN / 8)) * 8;
    const float4 v0 = *reinterpret_cast<const float4*>(&x[(size_t)m * KIN + k0]);
    const float4 v1 = *reinterpret_cast<const float4*>(&x[(size_t)m * KIN + k0 + 4]);
    const float4 b0 = *reinterpret_cast<const float4*>(&bdec[k0]);
    const float4 b1 = *reinterpret_cast<const float4*>(&bdec[k0 + 4]);
    uint4 o;
    o.x = (unsigned)f2bf(v0.x - b0.x) | ((unsigned)f2bf(v0.y - b0.y) << 16);
    o.y = (unsigned)f2bf(v0.z - b0.z) | ((unsigned)f2bf(v0.w - b0.w) << 16);
    o.z = (unsigned)f2bf(v1.x - b1.x) | ((unsigned)f2bf(v1.y - b1.y) << 16);
    o.w = (unsigned)f2bf(v1.z - b1.z) | ((unsigned)f2bf(v1.w - b1.w) << 16);
    *reinterpret_cast<uint4*>(&Aws[(size_t)m * KIN + (k0 ^ ((m & 7) * 8))]) = o;
}

// ---------------------------------------------------------------------------
// Prep B: WT[n][k] = W_enc[k][n] (fp32) and optionally swizzled bf16 Bws
// ---------------------------------------------------------------------------
__global__ __launch_bounds__(256) void transpose_wenc(
    const float* __restrict__ W, float* __restrict__ WT,
    unsigned short* __restrict__ Bws)
{
    __shared__ float t[32][33];
    const int bn = blockIdx.x * 32;
    const int bk = blockIdx.y * 32;
    const int lx = threadIdx.x & 31;
    const int ly = threadIdx.x >> 5;
#pragma unroll
    for (int r = 0; r < 4; ++r)
        t[ly + 8 * r][lx] = W[(size_t)(bk + ly + 8 * r) * NSAE + bn + lx];
    __syncthreads();
#pragma unroll
    for (int r = 0; r < 4; ++r) {
        const int n = bn + ly + 8 * r;
        const int k = bk + lx;
        const float v = t[lx][ly + 8 * r];
        WT[(size_t)n * KIN + k] = v;
        if (Bws) Bws[(size_t)n * KIN + (k ^ ((n & 7) * 8))] = f2bf(v);
    }
}

// ---------------------------------------------------------------------------
// Prep C: WdB = bf16(W_dec), same [NSAE][KIN] layout (halves decode traffic)
// ---------------------------------------------------------------------------
__global__ __launch_bounds__(256) void conv_wdec(
    const float* __restrict__ W, unsigned short* __restrict__ WB)
{
    const size_t t = (size_t)blockIdx.x * 256 + threadIdx.x;  // NSAE*KIN/8
    const float4 v0 = *reinterpret_cast<const float4*>(&W[t * 8]);
    const float4 v1 = *reinterpret_cast<const float4*>(&W[t * 8 + 4]);
    uint4 o;
    o.x = (unsigned)f2bf(v0.x) | ((unsigned)f2bf(v0.y) << 16);
    o.y = (unsigned)f2bf(v0.z) | ((unsigned)f2bf(v0.w) << 16);
    o.z = (unsigned)f2bf(v1.x) | ((unsigned)f2bf(v1.y) << 16);
    o.w = (unsigned)f2bf(v1.z) | ((unsigned)f2bf(v1.w) << 16);
    *reinterpret_cast<uint4*>(&WB[t * 8]) = o;
}

// ---------------------------------------------------------------------------
// Kernel 1: bf16 MFMA screening GEMM -> bf16 pre (row-strided).
// 256x128 block tile, 8 waves (4 row x 2 col), per-wave 64x64 unchanged.
// B staged once per 256 output rows (halves redundant B staging).
// ---------------------------------------------------------------------------
__global__ __launch_bounds__(512) void sae_encode_mfma(
    const unsigned short* __restrict__ Aws,
    const unsigned short* __restrict__ Bws,
    const float* __restrict__ benc,
    unsigned short* __restrict__ preB,
    int rstride)
{
    __shared__ __align__(16) unsigned short Al[256 * 64];   // 32 KB
    __shared__ __align__(16) unsigned short Bl[128 * 64];   // 16 KB

    const int tid = threadIdx.x;
    const int w   = tid >> 6;            // 0..7
    const int l   = tid & 63;
    const int wr  = (w >> 1) * 64;       // 0,64,128,192
    const int wc  = (w & 1) * 64;        // 0,64
    const int row0 = blockIdx.y * 256;
    const int col0 = blockIdx.x * 128;

    ffrag acc[4][4];
#pragma unroll
    for (int i = 0; i < 4; ++i)
#pragma unroll
        for (int j = 0; j < 4; ++j)
#pragma unroll
            for (int r = 0; r < 4; ++r) acc[i][j][r] = 0.0f;

    // A staging: wave w covers rows [w*32, w*32+32) of 256; 4 issues x 8 rows
    const int sra = w * 32 + (l >> 3);
    // B staging: wave w covers rows [w*16, w*16+16) of 128; 2 issues x 8 rows
    const int srb = w * 16 + (l >> 3);
    const int sb  = (l & 7) * 16;
    const char* Ag = (const char*)(Aws + (size_t)(row0 + sra) * KIN) + sb;
    const char* Bg = (const char*)(Bws + (size_t)(col0 + srb) * KIN) + sb;

    const int g = l >> 4;
    const int q = l & 15;

    for (int kt = 0; kt < KIN / 64; ++kt) {
#pragma unroll
        for (int i = 0; i < 4; ++i)
            async_load16(Ag + (size_t)i * 8 * (KIN * 2) + kt * 128,
                         &Al[(w * 32 + i * 8) * 64]);
#pragma unroll
        for (int i = 0; i < 2; ++i)
            async_load16(Bg + (size_t)i * 8 * (KIN * 2) + kt * 128,
                         &Bl[(w * 16 + i * 8) * 64]);
        __syncthreads();
#pragma unroll
        for (int kk = 0; kk < 2; ++kk) {
            bfrag af[4], bf[4];
#pragma unroll
            for (int mf = 0; mf < 4; ++mf) {
                const int m = wr + mf * 16 + q;
                af[mf] = *reinterpret_cast<const bfrag*>(
                    &Al[m * 64 + ((kk * 32 + g * 8) ^ ((m & 7) * 8))]);
            }
#pragma unroll
            for (int nf = 0; nf < 4; ++nf) {
                const int n = wc + nf * 16 + q;
                bf[nf] = *reinterpret_cast<const bfrag*>(
                    &Bl[n * 64 + ((kk * 32 + g * 8) ^ ((n & 7) * 8))]);
            }
#pragma unroll
            for (int mf = 0; mf < 4; ++mf)
#pragma unroll
                for (int nf = 0; nf < 4; ++nf)
                    acc[mf][nf] = __builtin_amdgcn_mfma_f32_16x16x32_bf16(
                        af[mf], bf[nf], acc[mf][nf], 0, 0, 0);
        }
        __syncthreads();
    }

    // epilogue: + b_enc, relu, store bf16 (row stride = rstride ushorts)
#pragma unroll
    for (int nf = 0; nf < 4; ++nf) {
        const int gc = col0 + wc + nf * 16 + q;
        const float be = benc[gc];
#pragma unroll
        for (int mf = 0; mf < 4; ++mf) {
            const int gr = row0 + wr + mf * 16 + g * 4;
#pragma unroll
            for (int r = 0; r < 4; ++r)
                preB[(size_t)(gr + r) * rstride + gc] =
                    f2bf(fmaxf(acc[mf][nf][r] + be, 0.0f));
        }
    }
}

// ---------------------------------------------------------------------------
// Kernel 2: fused select+decode with certainty-band refinement (R14 form).
// ---------------------------------------------------------------------------
__global__ __launch_bounds__(256) void sae_fused(
    const float* __restrict__ x,
    const float* __restrict__ WT,        // [NSAE][KIN] fp32
    const float* __restrict__ benc,
    const float* __restrict__ bdec,
    const unsigned short* __restrict__ WdB,  // [NSAE][KIN] bf16
    float* __restrict__ xhat,            // [MB][KIN]
    float* __restrict__ z)               // [MB][NSAE]; first 32KB of row = preB
{
    const int row = blockIdx.x;
    const int tid = threadIdx.x;
    float* rp = z + (size_t)row * NSAE;
    const unsigned short* pp = (const unsigned short*)rp;

    __shared__ int      hist[NBIN];
    __shared__ int      s_v32;
    __shared__ int      s_cc;
    __shared__ int      s_uc;
    __shared__ int      cidx[CMAX];
    __shared__ float    cval[CMAX];
    __shared__ int      uidx[UMAX];
    __shared__ float    ukey[UMAX];
    __shared__ double   xsd[KIN];
    __shared__ float    selv[KSEL];
    __shared__ int      selp[KSEL];

    // ---- stage this row's bf16 pre into registers ----
    uint4 u4[8];
#pragma unroll
    for (int i = 0; i < 8; ++i)
        u4[i] = reinterpret_cast<const uint4*>(pp)[i * 256 + tid];

    for (int i = tid; i < NBIN; i += 256) hist[i] = 0;
    if (tid == 0) { s_cc = 0; s_uc = 0; s_v32 = -1; }
    if (tid < KSEL) { selv[tid] = 0.0f; selp[tid] = 0; }
    for (int i = tid; i < KIN; i += 256)
        xsd[i] = (double)x[(size_t)row * KIN + i] - (double)bdec[i];
    __syncthreads();

    // ---- exact bf16-resolution histogram of values >= 1.0 (0x3F80) ----
#pragma unroll
    for (int i = 0; i < 8; ++i) {
        const unsigned wv[4] = {u4[i].x, u4[i].y, u4[i].z, u4[i].w};
#pragma unroll
        for (int j = 0; j < 4; ++j) {
            const unsigned lo = wv[j] & 0xFFFFu;
            const unsigned hi = wv[j] >> 16;
            if (lo >= 0x3F80u) {
                int b = (int)(lo - 0x3F80u); if (b > NBIN - 1) b = NBIN - 1;
                atomicAdd(&hist[b], 1);
            }
            if (hi >= 0x3F80u) {
                int b = (int)(hi - 0x3F80u); if (b > NBIN - 1) b = NBIN - 1;
                atomicAdd(&hist[b], 1);
            }
        }
    }

    // ---- issue z-row zeroing (drains under the scan/refine) ----
    const float4 z4 = make_float4(0.0f, 0.0f, 0.0f, 0.0f);
#pragma unroll
    for (int i = 0; i < 16; ++i)
        reinterpret_cast<float4*>(rp)[i * 256 + tid] = z4;
    __syncthreads();

    // ---- wave 0: suffix-scan 1024 bins -> screened rank-32 bin ----
    if (tid < 64) {
        int hb[16]; int s16 = 0;
#pragma unroll
        for (int b = 0; b < 16; ++b) { hb[b] = hist[tid * 16 + b]; s16 += hb[b]; }
        int suf = s16;
#pragma unroll
        for (int off = 1; off < 64; off <<= 1) {
            const int v = __shfl_down(suf, off);
            if (tid + off < 64) suf += v;
        }
        const int tail  = suf - s16;
        const int total = __shfl(suf, 0);
        if (total >= KSEL && tail < KSEL && suf >= KSEL) {
            int cum = tail;
#pragma unroll
            for (int b = 15; b >= 0; --b) {
                cum += hb[b];
                if (cum >= KSEL) { s_v32 = tid * 16 + b; break; }
            }
        }
    }
    __syncthreads();

    const int v32 = s_v32;
    unsigned Tlo, Thi;
    if (v32 >= 3 * BAND) {
        Tlo = 0x3F80u + (unsigned)(v32 - BAND);
        Thi = 0x3F80u + (unsigned)(v32 + BAND);
    } else {
        Tlo = 0x3F80u;
        Thi = 0xFFFFu;
    }

    // ---- collect certain-in and uncertain candidates ----
#pragma unroll
    for (int i = 0; i < 8; ++i) {
        const unsigned wv[4] = {u4[i].x, u4[i].y, u4[i].z, u4[i].w};
#pragma unroll
        for (int j = 0; j < 4; ++j) {
            const int base = (i * 256 + tid) * 8 + j * 2;
            const unsigned bb[2] = {wv[j] & 0xFFFFu, wv[j] >> 16};
#pragma unroll
            for (int h = 0; h < 2; ++h) {
                const unsigned b = bb[h];
                if (b > Thi) {
                    const int s = atomicAdd(&s_cc, 1);
                    if (s < CMAX) {
                        cidx[s] = base + h;
                        cval[s] = __uint_as_float(b << 16);
                    }
                } else if (b >= Tlo) {
                    const int s = atomicAdd(&s_uc, 1);
                    if (s < UMAX) uidx[s] = base + h;
                }
            }
        }
    }
    __syncthreads();
    const int C = (s_cc < KSEL) ? s_cc : KSEL;
    const int U = (s_uc < UMAX) ? s_uc : UMAX;
    const int need = KSEL - C;

    // ---- fp64 refinement of uncertain -> fp32 keys (R12 scalar form) ----
    for (int cnd = tid >> 2; cnd < U; cnd += 64) {
        const int lane = tid & 3;
        const int idx  = uidx[cnd];
        const float* wp = WT + (size_t)idx * KIN + lane;
        double acc = 0.0;
        for (int j = 0; j < KIN / 4; ++j)
            acc = fma(xsd[lane + j * 4], (double)wp[j * 4], acc);
        acc += __shfl_down(acc, 2, 4);
        acc += __shfl_down(acc, 1, 4);
        if (lane == 0)
            ukey[cnd] = fmaxf((float)(acc + (double)benc[idx]), 0.0f);
    }
    __syncthreads();

    // ---- fill selection: certains first, then top-need uncertain ----
    if (tid < C) { selv[tid] = cval[tid]; selp[tid] = cidx[tid]; }
    if (tid < U) {
        const float v = ukey[tid];
        const int   p = uidx[tid];
        int rank = 0;
        for (int j = 0; j < U; ++j) {
            const float vj = ukey[j];
            const int   pj = uidx[j];
            if (vj > v || (vj == v && pj < p)) ++rank;
        }
        if (rank < need) { selv[C + rank] = v; selp[C + rank] = p; }
    }
    __syncthreads();   // drains z-zero stores block-wide too

    // ---- scatter selection into the zeroed z row ----
    if (tid < KSEL && selv[tid] != 0.0f) rp[selp[tid]] = selv[tid];

    // ---- sparse decode from bf16 Wdec: xhat = b_dec + sum_j v_j*Wdec[p_j] ----
    const unsigned* Wd32 = (const unsigned*)WdB;   // [NSAE][KIN/2] packed pairs
#pragma unroll
    for (int pass = 0; pass < 2; ++pass) {
        const int u = tid + pass * 256;            // column pair index
        if (u < KIN / 2) {
            float a0 = bdec[2 * u];
            float a1 = bdec[2 * u + 1];
#pragma unroll 8
            for (int j = 0; j < KSEL; ++j) {
                const unsigned w = Wd32[(size_t)selp[j] * (KIN / 2) + u];
                a0 = fmaf(selv[j], __uint_as_float(w << 16), a0);
                a1 = fmaf(selv[j], __uint_as_float(w & 0xFFFF0000u), a1);
            }
            float2 o; o.x = a0; o.y = a1;
            *reinterpret_cast<float2*>(&xhat[(size_t)row * KIN + 2 * u]) = o;
        }
    }
}

// ---------------------------------------------------------------------------
// Fallback kernels (fp32 pipeline, used only when workspace is small)
// ---------------------------------------------------------------------------
__global__ __launch_bounds__(256) void sae_encode_gemm(
    const float* __restrict__ x,
    const float* __restrict__ Wenc,
    const float* __restrict__ benc,
    const float* __restrict__ bdec,
    float* __restrict__ pre)
{
    __shared__ float As[BKK][APAD];
    __shared__ float Bs[BKK][BN];

    const int tid  = threadIdx.x;
    const int tx   = tid & 15;
    const int ty   = tid >> 4;
    const int col0 = blockIdx.x * BN;
    const int row0 = blockIdx.y * BM;

    const int ar = tid >> 2;
    const int ac = (tid & 3) << 2;
    const int br = tid >> 5;
    const int bc = (tid & 31) << 2;

    float acc[8][8];
#pragma unroll
    for (int i = 0; i < 8; ++i)
#pragma unroll
        for (int j = 0; j < 8; ++j) acc[i][j] = 0.0f;

    for (int kt = 0; kt < KIN; kt += BKK) {
        const float bd0 = bdec[kt + ac + 0];
        const float bd1 = bdec[kt + ac + 1];
        const float bd2 = bdec[kt + ac + 2];
        const float bd3 = bdec[kt + ac + 3];
#pragma unroll
        for (int h = 0; h < 2; ++h) {
            const int r = ar + h * 64;
            const float4 av = *reinterpret_cast<const float4*>(
                &x[(size_t)(row0 + r) * KIN + kt + ac]);
            As[ac + 0][r] = av.x - bd0;
            As[ac + 1][r] = av.y - bd1;
            As[ac + 2][r] = av.z - bd2;
            As[ac + 3][r] = av.w - bd3;
        }
#pragma unroll
        for (int h = 0; h < 2; ++h) {
            const int r = br + h * 8;
            *reinterpret_cast<float4*>(&Bs[r][bc]) =
                *reinterpret_cast<const float4*>(
                    &Wenc[(size_t)(kt + r) * NSAE + col0 + bc]);
        }
        __syncthreads();

#pragma unroll
        for (int k = 0; k < BKK; ++k) {
            float a[8], b[8];
            *reinterpret_cast<float4*>(&a[0]) =
                *reinterpret_cast<const float4*>(&As[k][ty * 4]);
            *reinterpret_cast<float4*>(&a[4]) =
                *reinterpret_cast<const float4*>(&As[k][64 + ty * 4]);
            *reinterpret_cast<float4*>(&b[0]) =
                *reinterpret_cast<const float4*>(&Bs[k][tx * 4]);
            *reinterpret_cast<float4*>(&b[4]) =
                *reinterpret_cast<const float4*>(&Bs[k][64 + tx * 4]);
#pragma unroll
            for (int i = 0; i < 8; ++i)
#pragma unroll
                for (int j = 0; j < 8; ++j)
                    acc[i][j] = fmaf(a[i], b[j], acc[i][j]);
        }
        __syncthreads();
    }

#pragma unroll
    for (int i = 0; i < 8; ++i) {
        const int gr = row0 + ((i & 3) + ty * 4) + ((i >> 2) * 64);
#pragma unroll
        for (int jg = 0; jg < 2; ++jg) {
            const int gc = col0 + tx * 4 + jg * 64;
            float4 v;
            v.x = fmaxf(acc[i][jg * 4 + 0] + benc[gc + 0], 0.0f);
            v.y = fmaxf(acc[i][jg * 4 + 1] + benc[gc + 1], 0.0f);
            v.z = fmaxf(acc[i][jg * 4 + 2] + benc[gc + 2], 0.0f);
            v.w = fmaxf(acc[i][jg * 4 + 3] + benc[gc + 3], 0.0f);
            *reinterpret_cast<float4*>(&pre[(size_t)gr * NSAE + gc]) = v;
        }
    }
}

template <bool TR>
__global__ __launch_bounds__(256) void sae_topk_decode(
    float* __restrict__ z,
    const float* __restrict__ x,
    const float* __restrict__ Wcol,
    const float* __restrict__ benc,
    const float* __restrict__ Wdec,
    const float* __restrict__ bdec,
    float* __restrict__ xhat)
{
    const int row = blockIdx.x;
    const int tid = threadIdx.x;
    float* rp = z + (size_t)row * NSAE;

    __shared__ int      hist[16];
    __shared__ unsigned s_pfx;
    __shared__ int      s_need;
    __shared__ int      s_nc;
    __shared__ int      candp[NCMAX];
    __shared__ float    candf[NCMAX];
    __shared__ double   xsd[KIN];
    __shared__ float    selv[KSEL];
    __shared__ int      selp[KSEL];

    uint4 e[16];
#pragma unroll
    for (int i = 0; i < 16; ++i)
        e[i] = *reinterpret_cast<const uint4*>(&rp[i * 1024 + tid * 4]);

    if (tid == 0) { s_pfx = 0u; s_need = 64; s_nc = 0; }
    if (tid < 16) hist[tid] = 0;
    __syncthreads();

    for (int shift = 28; shift >= 0; shift -= 4) {
        const unsigned pfx   = s_pfx;
        const unsigned maskd = (shift == 28) ? 0u : (0xFFFFFFFFu << (shift + 4));
        int cnt[16];
#pragma unroll
        for (int d = 0; d < 16; ++d) cnt[d] = 0;
#pragma unroll
        for (int i = 0; i < 16; ++i) {
            const unsigned uu[4] = {e[i].x, e[i].y, e[i].z, e[i].w};
#pragma unroll
            for (int j = 0; j < 4; ++j)
                if ((uu[j] & maskd) == pfx) ++cnt[(uu[j] >> shift) & 15];
        }
#pragma unroll
        for (int d = 0; d < 16; ++d)
            if (cnt[d]) atomicAdd(&hist[d], cnt[d]);
        __syncthreads();
        if (tid == 0) {
            int cum = 0, sel = 0;
            const int need = s_need;
            for (int d = 15; d >= 0; --d) {
                const int c = hist[d];
                cum += c;
                if (cum >= need) { sel = d; s_need = need - (cum - c); break; }
            }
            s_pfx = pfx | ((unsigned)sel << shift);
        }
        __syncthreads();
        if (tid < 16) hist[tid] = 0;
        __syncthreads();
    }
    const unsigned T = s_pfx;

#pragma unroll
    for (int i = 0; i < 16; ++i) {
        const unsigned uu[4] = {e[i].x, e[i].y, e[i].z, e[i].w};
#pragma unroll
        for (int j = 0; j < 4; ++j) {
            if (uu[j] >= T) {
                const int slot = atomicAdd(&s_nc, 1);
                if (slot < NCMAX) candp[slot] = i * 1024 + tid * 4 + j;
            }
        }
    }
    if (tid < NCMAX) candf[tid] = -1.0f;
    for (int i = tid; i < KIN; i += 256)
        xsd[i] = (double)x[(size_t)row * KIN + i] - (double)bdec[i];
    __syncthreads();
    const int nc = (s_nc < NCMAX) ? s_nc : NCMAX;

    for (int cnd = tid >> 2; cnd < nc; cnd += 64) {
        const int lane = tid & 3;
        const int idx  = candp[cnd];
        double acc = 0.0;
        if (TR) {
            const float* wp = Wcol + (size_t)idx * KIN + lane;
            for (int j = 0; j < KIN / 4; ++j)
                acc = fma(xsd[lane + j * 4], (double)wp[j * 4], acc);
        } else {
            const float* wp = Wcol + idx;
            for (int j = 0; j < KIN / 4; ++j)
                acc = fma(xsd[lane + j * 4],
                          (double)wp[(size_t)(lane + j * 4) * NSAE], acc);
        }
        acc += __shfl_down(acc, 2, 4);
        acc += __shfl_down(acc, 1, 4);
        if (lane == 0)
            candf[cnd] = fmaxf((float)(acc + (double)benc[idx]), 0.0f);
    }
    __syncthreads();

    if (tid < KSEL) { selv[tid] = 0.0f; selp[tid] = 0; }
    __syncthreads();

    if (tid < nc) {
        const float v = candf[tid];
        const int   p = candp[tid];
        int rank = 0;
        for (int j = 0; j < nc; ++j) {
            const float vj = candf[j];
            const int   pj = candp[j];
            if (vj > v || (vj == v && pj < p)) ++rank;
        }
        if (rank < KSEL) { selv[rank] = v; selp[rank] = p; }
    }
    __syncthreads();

    const float4 zv4 = make_float4(0.0f, 0.0f, 0.0f, 0.0f);
#pragma unroll
    for (int i = 0; i < 16; ++i)
        *reinterpret_cast<float4*>(&rp[i * 1024 + tid * 4]) = zv4;
    __syncthreads();
    if (tid < KSEL && selv[tid] != 0.0f) rp[selp[tid]] = selv[tid];

#pragma unroll
    for (int t = 0; t < 3; ++t) {
        const int c = tid + t * 256;
        float accv = bdec[c];
#pragma unroll 8
        for (int j = 0; j < KSEL; ++j)
            accv = fmaf(selv[j], Wdec[(size_t)selp[j] * KIN + c], accv);
        xhat[(size_t)row * KIN + c] = accv;
    }
}

// ---------------------------------------------------------------------------
extern "C" void kernel_launch(void* const* d_in, const int* in_sizes, int n_in,
                              void* d_out, int out_size, void* d_ws, size_t ws_size,
                              hipStream_t stream) {
    const float* x    = (const float*)d_in[0];
    const float* Wenc = (const float*)d_in[1];
    const float* benc = (const float*)d_in[2];
    const float* Wdec = (const float*)d_in[3];
    const float* bdec = (const float*)d_in[4];

    float* xhat = (float*)d_out;                        // [8192, 768]
    float* z    = (float*)d_out + (size_t)MB * KIN;     // [8192, 16384]

    const size_t szA  = (size_t)MB * KIN * 2;           // 12.58 MB
    const size_t szB  = (size_t)NSAE * KIN * 2;         // 25.17 MB
    const size_t szWT = (size_t)NSAE * KIN * 4;         // 50.33 MB
    const size_t szWd = (size_t)NSAE * KIN * 2;         // 25.17 MB

    if (ws_size >= szA + szB + szWT + szWd) {
        unsigned short* Aws = (unsigned short*)d_ws;
        unsigned short* Bws = (unsigned short*)((char*)d_ws + szA);
        float*          WT  = (float*)((char*)d_ws + szA + szB);
        unsigned short* WdB = (unsigned short*)((char*)d_ws + szA + szB + szWT);
        unsigned short* preB = (unsigned short*)z;      // row-strided bf16 pre
        conv_x<<<dim3(MB * (KIN / 8) / 256), dim3(256), 0, stream>>>(x, bdec, Aws);
        transpose_wenc<<<dim3(NSAE / 32, KIN / 32), dim3(256), 0, stream>>>(Wenc, WT, Bws);
        conv_wdec<<<dim3((NSAE / 8) * (KIN / 256)), dim3(256), 0, stream>>>(Wdec, WdB);
        sae_encode_mfma<<<dim3(NSAE / 128, MB / 256), dim3(512), 0, stream>>>(
            Aws, Bws, benc, preB, NSAE * 2);
        sae_fused<<<dim3(MB), dim3(256), 0, stream>>>(
            x, WT, benc, bdec, WdB, xhat, z);
    } else if (ws_size >= szWT) {
        float* WT = (float*)d_ws;
        sae_encode_gemm<<<dim3(NSAE / BN, MB / BM), dim3(256), 0, stream>>>(
            x, Wenc, benc, bdec, z);
        transpose_wenc<<<dim3(NSAE / 32, KIN / 32), dim3(256), 0, stream>>>(Wenc, WT, nullptr);
        sae_topk_decode<true><<<dim3(MB), dim3(256), 0, stream>>>(
            z, x, WT, benc, Wdec, bdec, xhat);
    } else {
        sae_encode_gemm<<<dim3(NSAE / BN, MB / BM), dim3(256), 0, stream>>>(
            x, Wenc, benc, bdec, z);
        sae_topk_decode<false><<<dim3(MB), dim3(256), 0, stream>>>(
            z, x, Wenc, benc, Wdec, bdec, xhat);
    }
}

// Round 18
// 592.557 us; speedup vs baseline: 1.0698x; 1.0417x over previous
//
#include <hip/hip_runtime.h>
#include <cstdint>
#include <cstddef>

#define MB    8192
#define NSAE  16384
#define KIN   768
#define KSEL  32
#define NBIN  1024
#define BAND  8      // +/- band (bf16 ULP bins) around screened rank-32
#define UMAX  160    // uncertain-candidate capacity (typ ~25)
#define CMAX  40     // certain-in capacity (provably <= 31)
#define NCMAX 128    // legacy fallback kernels

#define BM  128
#define BN  128
#define BKK 16
#define APAD 132

#define EPAD 144     // epilogue LDS row stride in ushorts (128 + 16 pad)

typedef __attribute__((ext_vector_type(8))) short bfrag;
typedef __attribute__((ext_vector_type(4))) float ffrag;

__device__ __forceinline__ unsigned short f2bf(float f) {
    unsigned u = __float_as_uint(f);
    return (unsigned short)((u + 0x7FFFu + ((u >> 16) & 1u)) >> 16);
}

__device__ __forceinline__ void async_load16(const void* gsrc, void* ldsdst) {
    __builtin_amdgcn_global_load_lds(
        (const __attribute__((address_space(1))) unsigned int*)gsrc,
        (__attribute__((address_space(3))) unsigned int*)ldsdst,
        16, 0, 0);
}

// ---------------------------------------------------------------------------
// Prep A: Aws[m][k ^ ((m&7)*8)] = bf16(x[m][k] - bdec[k])   (swizzled bf16)
// ---------------------------------------------------------------------------
__global__ __launch_bounds__(256) void conv_x(
    const float* __restrict__ x, const float* __restrict__ bdec,
    unsigned short* __restrict__ Aws)
{
    const int t  = blockIdx.x * 256 + threadIdx.x;
    const int m  = t / (KIN / 8);
    const int k0 = (t % (KIN / 8)) * 8;
    const float4 v0 = *reinterpret_cast<const float4*>(&x[(size_t)m * KIN + k0]);
    const float4 v1 = *reinterpret_cast<const float4*>(&x[(size_t)m * KIN + k0 + 4]);
    const float4 b0 = *reinterpret_cast<const float4*>(&bdec[k0]);
    const float4 b1 = *reinterpret_cast<const float4*>(&bdec[k0 + 4]);
    uint4 o;
    o.x = (unsigned)f2bf(v0.x - b0.x) | ((unsigned)f2bf(v0.y - b0.y) << 16);
    o.y = (unsigned)f2bf(v0.z - b0.z) | ((unsigned)f2bf(v0.w - b0.w) << 16);
    o.z = (unsigned)f2bf(v1.x - b1.x) | ((unsigned)f2bf(v1.y - b1.y) << 16);
    o.w = (unsigned)f2bf(v1.z - b1.z) | ((unsigned)f2bf(v1.w - b1.w) << 16);
    *reinterpret_cast<uint4*>(&Aws[(size_t)m * KIN + (k0 ^ ((m & 7) * 8))]) = o;
}

// ---------------------------------------------------------------------------
// Prep B: WT[n][k] = W_enc[k][n] (fp32) and optionally swizzled bf16 Bws
// ---------------------------------------------------------------------------
__global__ __launch_bounds__(256) void transpose_wenc(
    const float* __restrict__ W, float* __restrict__ WT,
    unsigned short* __restrict__ Bws)
{
    __shared__ float t[32][33];
    const int bn = blockIdx.x * 32;
    const int bk = blockIdx.y * 32;
    const int lx = threadIdx.x & 31;
    const int ly = threadIdx.x >> 5;
#pragma unroll
    for (int r = 0; r < 4; ++r)
        t[ly + 8 * r][lx] = W[(size_t)(bk + ly + 8 * r) * NSAE + bn + lx];
    __syncthreads();
#pragma unroll
    for (int r = 0; r < 4; ++r) {
        const int n = bn + ly + 8 * r;
        const int k = bk + lx;
        const float v = t[lx][ly + 8 * r];
        WT[(size_t)n * KIN + k] = v;
        if (Bws) Bws[(size_t)n * KIN + (k ^ ((n & 7) * 8))] = f2bf(v);
    }
}

// ---------------------------------------------------------------------------
// Prep C: WdB = bf16(W_dec), same [NSAE][KIN] layout (halves decode traffic)
// ---------------------------------------------------------------------------
__global__ __launch_bounds__(256) void conv_wdec(
    const float* __restrict__ W, unsigned short* __restrict__ WB)
{
    const size_t t = (size_t)blockIdx.x * 256 + threadIdx.x;  // NSAE*KIN/8
    const float4 v0 = *reinterpret_cast<const float4*>(&W[t * 8]);
    const float4 v1 = *reinterpret_cast<const float4*>(&W[t * 8 + 4]);
    uint4 o;
    o.x = (unsigned)f2bf(v0.x) | ((unsigned)f2bf(v0.y) << 16);
    o.y = (unsigned)f2bf(v0.z) | ((unsigned)f2bf(v0.w) << 16);
    o.z = (unsigned)f2bf(v1.x) | ((unsigned)f2bf(v1.y) << 16);
    o.w = (unsigned)f2bf(v1.z) | ((unsigned)f2bf(v1.w) << 16);
    *reinterpret_cast<uint4*>(&WB[t * 8]) = o;
}

// ---------------------------------------------------------------------------
// Kernel 1: bf16 MFMA screening GEMM -> bf16 pre (row-strided).
// 256x128 block tile, 8 waves (4 row x 2 col).
// NEW: vectorized epilogue -- fragments staged to LDS (reusing the staging
// buffer, +16-ushort pad for conflict-free fill), then uint4 global stores
// (256B contiguous segments) instead of 64 scalar 2B stores per thread.
// ---------------------------------------------------------------------------
__global__ __launch_bounds__(512) void sae_encode_mfma(
    const unsigned short* __restrict__ Aws,
    const unsigned short* __restrict__ Bws,
    const float* __restrict__ benc,
    unsigned short* __restrict__ preB,
    int rstride)
{
    __shared__ __align__(16) unsigned short Sh[256 * 64 + 128 * 64]; // 48 KB
    unsigned short* Al = Sh;                // [256][64]
    unsigned short* Bl = Sh + 256 * 64;     // [128][64]

    const int tid = threadIdx.x;
    const int w   = tid >> 6;            // 0..7
    const int l   = tid & 63;
    const int wr  = (w >> 1) * 64;       // 0,64,128,192
    const int wc  = (w & 1) * 64;        // 0,64
    const int row0 = blockIdx.y * 256;
    const int col0 = blockIdx.x * 128;

    ffrag acc[4][4];
#pragma unroll
    for (int i = 0; i < 4; ++i)
#pragma unroll
        for (int j = 0; j < 4; ++j)
#pragma unroll
            for (int r = 0; r < 4; ++r) acc[i][j][r] = 0.0f;

    // A staging: wave w covers rows [w*32, w*32+32) of 256; 4 issues x 8 rows
    const int sra = w * 32 + (l >> 3);
    // B staging: wave w covers rows [w*16, w*16+16) of 128; 2 issues x 8 rows
    const int srb = w * 16 + (l >> 3);
    const int sb  = (l & 7) * 16;
    const char* Ag = (const char*)(Aws + (size_t)(row0 + sra) * KIN) + sb;
    const char* Bg = (const char*)(Bws + (size_t)(col0 + srb) * KIN) + sb;

    const int g = l >> 4;
    const int q = l & 15;

    for (int kt = 0; kt < KIN / 64; ++kt) {
#pragma unroll
        for (int i = 0; i < 4; ++i)
            async_load16(Ag + (size_t)i * 8 * (KIN * 2) + kt * 128,
                         &Al[(w * 32 + i * 8) * 64]);
#pragma unroll
        for (int i = 0; i < 2; ++i)
            async_load16(Bg + (size_t)i * 8 * (KIN * 2) + kt * 128,
                         &Bl[(w * 16 + i * 8) * 64]);
        __syncthreads();
#pragma unroll
        for (int kk = 0; kk < 2; ++kk) {
            bfrag af[4], bf[4];
#pragma unroll
            for (int mf = 0; mf < 4; ++mf) {
                const int m = wr + mf * 16 + q;
                af[mf] = *reinterpret_cast<const bfrag*>(
                    &Al[m * 64 + ((kk * 32 + g * 8) ^ ((m & 7) * 8))]);
            }
#pragma unroll
            for (int nf = 0; nf < 4; ++nf) {
                const int n = wc + nf * 16 + q;
                bf[nf] = *reinterpret_cast<const bfrag*>(
                    &Bl[n * 64 + ((kk * 32 + g * 8) ^ ((n & 7) * 8))]);
            }
#pragma unroll
            for (int mf = 0; mf < 4; ++mf)
#pragma unroll
                for (int nf = 0; nf < 4; ++nf)
                    acc[mf][nf] = __builtin_amdgcn_mfma_f32_16x16x32_bf16(
                        af[mf], bf[nf], acc[mf][nf], 0, 0, 0);
        }
        __syncthreads();
    }

    // ---- vectorized epilogue: two 128-row halves via LDS restage ----
    // Sh reused as [128][EPAD] ushorts (36 KB). Fill is conflict-free:
    // bank = (lr*72 + lc/2) % 32 = const + g*8 + q/2 -> 32 banks, 2-way.
    float be[4];
#pragma unroll
    for (int nf = 0; nf < 4; ++nf)
        be[nf] = benc[col0 + wc + nf * 16 + q];

#pragma unroll
    for (int h = 0; h < 2; ++h) {
        if ((w >> 2) == h) {
            const int lrb = (wr & 63) + ((w >> 1) & 1) * 64;  // wr - h*128
#pragma unroll
            for (int nf = 0; nf < 4; ++nf) {
                const int lc = wc + nf * 16 + q;
#pragma unroll
                for (int mf = 0; mf < 4; ++mf) {
                    const int lr0 = lrb + mf * 16 + g * 4;
#pragma unroll
                    for (int r = 0; r < 4; ++r)
                        Sh[(lr0 + r) * EPAD + lc] =
                            f2bf(fmaxf(acc[mf][nf][r] + be[nf], 0.0f));
                }
            }
        }
        __syncthreads();
        // store 128 rows x 256B with uint4: 2048 vec4 / 512 thr = 4 each
#pragma unroll
        for (int i = 0; i < 4; ++i) {
            const int idx = i * 512 + tid;       // 0..2047
            const int r   = idx >> 4;            // 0..127
            const int c   = (idx & 15) * 8;      // 0..120
            *reinterpret_cast<uint4*>(
                &preB[(size_t)(row0 + h * 128 + r) * rstride + col0 + c]) =
                *reinterpret_cast<const uint4*>(&Sh[r * EPAD + c]);
        }
        __syncthreads();
    }
}

// ---------------------------------------------------------------------------
// Kernel 2: fused select+decode with certainty-band refinement (R14 form).
// ---------------------------------------------------------------------------
__global__ __launch_bounds__(256) void sae_fused(
    const float* __restrict__ x,
    const float* __restrict__ WT,        // [NSAE][KIN] fp32
    const float* __restrict__ benc,
    const float* __restrict__ bdec,
    const unsigned short* __restrict__ WdB,  // [NSAE][KIN] bf16
    float* __restrict__ xhat,            // [MB][KIN]
    float* __restrict__ z)               // [MB][NSAE]; first 32KB of row = preB
{
    const int row = blockIdx.x;
    const int tid = threadIdx.x;
    float* rp = z + (size_t)row * NSAE;
    const unsigned short* pp = (const unsigned short*)rp;

    __shared__ int      hist[NBIN];
    __shared__ int      s_v32;
    __shared__ int      s_cc;
    __shared__ int      s_uc;
    __shared__ int      cidx[CMAX];
    __shared__ float    cval[CMAX];
    __shared__ int      uidx[UMAX];
    __shared__ float    ukey[UMAX];
    __shared__ double   xsd[KIN];
    __shared__ float    selv[KSEL];
    __shared__ int      selp[KSEL];

    // ---- stage this row's bf16 pre into registers ----
    uint4 u4[8];
#pragma unroll
    for (int i = 0; i < 8; ++i)
        u4[i] = reinterpret_cast<const uint4*>(pp)[i * 256 + tid];

    for (int i = tid; i < NBIN; i += 256) hist[i] = 0;
    if (tid == 0) { s_cc = 0; s_uc = 0; s_v32 = -1; }
    if (tid < KSEL) { selv[tid] = 0.0f; selp[tid] = 0; }
    for (int i = tid; i < KIN; i += 256)
        xsd[i] = (double)x[(size_t)row * KIN + i] - (double)bdec[i];
    __syncthreads();

    // ---- exact bf16-resolution histogram of values >= 1.0 (0x3F80) ----
#pragma unroll
    for (int i = 0; i < 8; ++i) {
        const unsigned wv[4] = {u4[i].x, u4[i].y, u4[i].z, u4[i].w};
#pragma unroll
        for (int j = 0; j < 4; ++j) {
            const unsigned lo = wv[j] & 0xFFFFu;
            const unsigned hi = wv[j] >> 16;
            if (lo >= 0x3F80u) {
                int b = (int)(lo - 0x3F80u); if (b > NBIN - 1) b = NBIN - 1;
                atomicAdd(&hist[b], 1);
            }
            if (hi >= 0x3F80u) {
                int b = (int)(hi - 0x3F80u); if (b > NBIN - 1) b = NBIN - 1;
                atomicAdd(&hist[b], 1);
            }
        }
    }

    // ---- issue z-row zeroing (drains under the scan/refine) ----
    const float4 z4 = make_float4(0.0f, 0.0f, 0.0f, 0.0f);
#pragma unroll
    for (int i = 0; i < 16; ++i)
        reinterpret_cast<float4*>(rp)[i * 256 + tid] = z4;
    __syncthreads();

    // ---- wave 0: suffix-scan 1024 bins -> screened rank-32 bin ----
    if (tid < 64) {
        int hb[16]; int s16 = 0;
#pragma unroll
        for (int b = 0; b < 16; ++b) { hb[b] = hist[tid * 16 + b]; s16 += hb[b]; }
        int suf = s16;
#pragma unroll
        for (int off = 1; off < 64; off <<= 1) {
            const int v = __shfl_down(suf, off);
            if (tid + off < 64) suf += v;
        }
        const int tail  = suf - s16;
        const int total = __shfl(suf, 0);
        if (total >= KSEL && tail < KSEL && suf >= KSEL) {
            int cum = tail;
#pragma unroll
            for (int b = 15; b >= 0; --b) {
                cum += hb[b];
                if (cum >= KSEL) { s_v32 = tid * 16 + b; break; }
            }
        }
    }
    __syncthreads();

    const int v32 = s_v32;
    unsigned Tlo, Thi;
    if (v32 >= 3 * BAND) {
        Tlo = 0x3F80u + (unsigned)(v32 - BAND);
        Thi = 0x3F80u + (unsigned)(v32 + BAND);
    } else {
        Tlo = 0x3F80u;
        Thi = 0xFFFFu;
    }

    // ---- collect certain-in and uncertain candidates ----
#pragma unroll
    for (int i = 0; i < 8; ++i) {
        const unsigned wv[4] = {u4[i].x, u4[i].y, u4[i].z, u4[i].w};
#pragma unroll
        for (int j = 0; j < 4; ++j) {
            const int base = (i * 256 + tid) * 8 + j * 2;
            const unsigned bb[2] = {wv[j] & 0xFFFFu, wv[j] >> 16};
#pragma unroll
            for (int h = 0; h < 2; ++h) {
                const unsigned b = bb[h];
                if (b > Thi) {
                    const int s = atomicAdd(&s_cc, 1);
                    if (s < CMAX) {
                        cidx[s] = base + h;
                        cval[s] = __uint_as_float(b << 16);
                    }
                } else if (b >= Tlo) {
                    const int s = atomicAdd(&s_uc, 1);
                    if (s < UMAX) uidx[s] = base + h;
                }
            }
        }
    }
    __syncthreads();
    const int C = (s_cc < KSEL) ? s_cc : KSEL;
    const int U = (s_uc < UMAX) ? s_uc : UMAX;
    const int need = KSEL - C;

    // ---- fp64 refinement of uncertain -> fp32 keys (R12 scalar form) ----
    for (int cnd = tid >> 2; cnd < U; cnd += 64) {
        const int lane = tid & 3;
        const int idx  = uidx[cnd];
        const float* wp = WT + (size_t)idx * KIN + lane;
        double acc = 0.0;
        for (int j = 0; j < KIN / 4; ++j)
            acc = fma(xsd[lane + j * 4], (double)wp[j * 4], acc);
        acc += __shfl_down(acc, 2, 4);
        acc += __shfl_down(acc, 1, 4);
        if (lane == 0)
            ukey[cnd] = fmaxf((float)(acc + (double)benc[idx]), 0.0f);
    }
    __syncthreads();

    // ---- fill selection: certains first, then top-need uncertain ----
    if (tid < C) { selv[tid] = cval[tid]; selp[tid] = cidx[tid]; }
    if (tid < U) {
        const float v = ukey[tid];
        const int   p = uidx[tid];
        int rank = 0;
        for (int j = 0; j < U; ++j) {
            const float vj = ukey[j];
            const int   pj = uidx[j];
            if (vj > v || (vj == v && pj < p)) ++rank;
        }
        if (rank < need) { selv[C + rank] = v; selp[C + rank] = p; }
    }
    __syncthreads();   // drains z-zero stores block-wide too

    // ---- scatter selection into the zeroed z row ----
    if (tid < KSEL && selv[tid] != 0.0f) rp[selp[tid]] = selv[tid];

    // ---- sparse decode from bf16 Wdec: xhat = b_dec + sum_j v_j*Wdec[p_j] ----
    const unsigned* Wd32 = (const unsigned*)WdB;   // [NSAE][KIN/2] packed pairs
#pragma unroll
    for (int pass = 0; pass < 2; ++pass) {
        const int u = tid + pass * 256;            // column pair index
        if (u < KIN / 2) {
            float a0 = bdec[2 * u];
            float a1 = bdec[2 * u + 1];
#pragma unroll 8
            for (int j = 0; j < KSEL; ++j) {
                const unsigned w = Wd32[(size_t)selp[j] * (KIN / 2) + u];
                a0 = fmaf(selv[j], __uint_as_float(w << 16), a0);
                a1 = fmaf(selv[j], __uint_as_float(w & 0xFFFF0000u), a1);
            }
            float2 o; o.x = a0; o.y = a1;
            *reinterpret_cast<float2*>(&xhat[(size_t)row * KIN + 2 * u]) = o;
        }
    }
}

// ---------------------------------------------------------------------------
// Fallback kernels (fp32 pipeline, used only when workspace is small)
// ---------------------------------------------------------------------------
__global__ __launch_bounds__(256) void sae_encode_gemm(
    const float* __restrict__ x,
    const float* __restrict__ Wenc,
    const float* __restrict__ benc,
    const float* __restrict__ bdec,
    float* __restrict__ pre)
{
    __shared__ float As[BKK][APAD];
    __shared__ float Bs[BKK][BN];

    const int tid  = threadIdx.x;
    const int tx   = tid & 15;
    const int ty   = tid >> 4;
    const int col0 = blockIdx.x * BN;
    const int row0 = blockIdx.y * BM;

    const int ar = tid >> 2;
    const int ac = (tid & 3) << 2;
    const int br = tid >> 5;
    const int bc = (tid & 31) << 2;

    float acc[8][8];
#pragma unroll
    for (int i = 0; i < 8; ++i)
#pragma unroll
        for (int j = 0; j < 8; ++j) acc[i][j] = 0.0f;

    for (int kt = 0; kt < KIN; kt += BKK) {
        const float bd0 = bdec[kt + ac + 0];
        const float bd1 = bdec[kt + ac + 1];
        const float bd2 = bdec[kt + ac + 2];
        const float bd3 = bdec[kt + ac + 3];
#pragma unroll
        for (int h = 0; h < 2; ++h) {
            const int r = ar + h * 64;
            const float4 av = *reinterpret_cast<const float4*>(
                &x[(size_t)(row0 + r) * KIN + kt + ac]);
            As[ac + 0][r] = av.x - bd0;
            As[ac + 1][r] = av.y - bd1;
            As[ac + 2][r] = av.z - bd2;
            As[ac + 3][r] = av.w - bd3;
        }
#pragma unroll
        for (int h = 0; h < 2; ++h) {
            const int r = br + h * 8;
            *reinterpret_cast<float4*>(&Bs[r][bc]) =
                *reinterpret_cast<const float4*>(
                    &Wenc[(size_t)(kt + r) * NSAE + col0 + bc]);
        }
        __syncthreads();

#pragma unroll
        for (int k = 0; k < BKK; ++k) {
            float a[8], b[8];
            *reinterpret_cast<float4*>(&a[0]) =
                *reinterpret_cast<const float4*>(&As[k][ty * 4]);
            *reinterpret_cast<float4*>(&a[4]) =
                *reinterpret_cast<const float4*>(&As[k][64 + ty * 4]);
            *reinterpret_cast<float4*>(&b[0]) =
                *reinterpret_cast<const float4*>(&Bs[k][tx * 4]);
            *reinterpret_cast<float4*>(&b[4]) =
                *reinterpret_cast<const float4*>(&Bs[k][64 + tx * 4]);
#pragma unroll
            for (int i = 0; i < 8; ++i)
#pragma unroll
                for (int j = 0; j < 8; ++j)
                    acc[i][j] = fmaf(a[i], b[j], acc[i][j]);
        }
        __syncthreads();
    }

#pragma unroll
    for (int i = 0; i < 8; ++i) {
        const int gr = row0 + ((i & 3) + ty * 4) + ((i >> 2) * 64);
#pragma unroll
        for (int jg = 0; jg < 2; ++jg) {
            const int gc = col0 + tx * 4 + jg * 64;
            float4 v;
            v.x = fmaxf(acc[i][jg * 4 + 0] + benc[gc + 0], 0.0f);
            v.y = fmaxf(acc[i][jg * 4 + 1] + benc[gc + 1], 0.0f);
            v.z = fmaxf(acc[i][jg * 4 + 2] + benc[gc + 2], 0.0f);
            v.w = fmaxf(acc[i][jg * 4 + 3] + benc[gc + 3], 0.0f);
            *reinterpret_cast<float4*>(&pre[(size_t)gr * NSAE + gc]) = v;
        }
    }
}

template <bool TR>
__global__ __launch_bounds__(256) void sae_topk_decode(
    float* __restrict__ z,
    const float* __restrict__ x,
    const float* __restrict__ Wcol,
    const float* __restrict__ benc,
    const float* __restrict__ Wdec,
    const float* __restrict__ bdec,
    float* __restrict__ xhat)
{
    const int row = blockIdx.x;
    const int tid = threadIdx.x;
    float* rp = z + (size_t)row * NSAE;

    __shared__ int      hist[16];
    __shared__ unsigned s_pfx;
    __shared__ int      s_need;
    __shared__ int      s_nc;
    __shared__ int      candp[NCMAX];
    __shared__ float    candf[NCMAX];
    __shared__ double   xsd[KIN];
    __shared__ float    selv[KSEL];
    __shared__ int      selp[KSEL];

    uint4 e[16];
#pragma unroll
    for (int i = 0; i < 16; ++i)
        e[i] = *reinterpret_cast<const uint4*>(&rp[i * 1024 + tid * 4]);

    if (tid == 0) { s_pfx = 0u; s_need = 64; s_nc = 0; }
    if (tid < 16) hist[tid] = 0;
    __syncthreads();

    for (int shift = 28; shift >= 0; shift -= 4) {
        const unsigned pfx   = s_pfx;
        const unsigned maskd = (shift == 28) ? 0u : (0xFFFFFFFFu << (shift + 4));
        int cnt[16];
#pragma unroll
        for (int d = 0; d < 16; ++d) cnt[d] = 0;
#pragma unroll
        for (int i = 0; i < 16; ++i) {
            const unsigned uu[4] = {e[i].x, e[i].y, e[i].z, e[i].w};
#pragma unroll
            for (int j = 0; j < 4; ++j)
                if ((uu[j] & maskd) == pfx) ++cnt[(uu[j] >> shift) & 15];
        }
#pragma unroll
        for (int d = 0; d < 16; ++d)
            if (cnt[d]) atomicAdd(&hist[d], cnt[d]);
        __syncthreads();
        if (tid == 0) {
            int cum = 0, sel = 0;
            const int need = s_need;
            for (int d = 15; d >= 0; --d) {
                const int c = hist[d];
                cum += c;
                if (cum >= need) { sel = d; s_need = need - (cum - c); break; }
            }
            s_pfx = pfx | ((unsigned)sel << shift);
        }
        __syncthreads();
        if (tid < 16) hist[tid] = 0;
        __syncthreads();
    }
    const unsigned T = s_pfx;

#pragma unroll
    for (int i = 0; i < 16; ++i) {
        const unsigned uu[4] = {e[i].x, e[i].y, e[i].z, e[i].w};
#pragma unroll
        for (int j = 0; j < 4; ++j) {
            if (uu[j] >= T) {
                const int slot = atomicAdd(&s_nc, 1);
                if (slot < NCMAX) candp[slot] = i * 1024 + tid * 4 + j;
            }
        }
    }
    if (tid < NCMAX) candf[tid] = -1.0f;
    for (int i = tid; i < KIN; i += 256)
        xsd[i] = (double)x[(size_t)row * KIN + i] - (double)bdec[i];
    __syncthreads();
    const int nc = (s_nc < NCMAX) ? s_nc : NCMAX;

    for (int cnd = tid >> 2; cnd < nc; cnd += 64) {
        const int lane = tid & 3;
        const int idx  = candp[cnd];
        double acc = 0.0;
        if (TR) {
            const float* wp = Wcol + (size_t)idx * KIN + lane;
            for (int j = 0; j < KIN / 4; ++j)
                acc = fma(xsd[lane + j * 4], (double)wp[j * 4], acc);
        } else {
            const float* wp = Wcol + idx;
            for (int j = 0; j < KIN / 4; ++j)
                acc = fma(xsd[lane + j * 4],
                          (double)wp[(size_t)(lane + j * 4) * NSAE], acc);
        }
        acc += __shfl_down(acc, 2, 4);
        acc += __shfl_down(acc, 1, 4);
        if (lane == 0)
            candf[cnd] = fmaxf((float)(acc + (double)benc[idx]), 0.0f);
    }
    __syncthreads();

    if (tid < KSEL) { selv[tid] = 0.0f; selp[tid] = 0; }
    __syncthreads();

    if (tid < nc) {
        const float v = candf[tid];
        const int   p = candp[tid];
        int rank = 0;
        for (int j = 0; j < nc; ++j) {
            const float vj = candf[j];
            const int   pj = candp[j];
            if (vj > v || (vj == v && pj < p)) ++rank;
        }
        if (rank < KSEL) { selv[rank] = v; selp[rank] = p; }
    }
    __syncthreads();

    const float4 zv4 = make_float4(0.0f, 0.0f, 0.0f, 0.0f);
#pragma unroll
    for (int i = 0; i < 16; ++i)
        *reinterpret_cast<float4*>(&rp[i * 1024 + tid * 4]) = zv4;
    __syncthreads();
    if (tid < KSEL && selv[tid] != 0.0f) rp[selp[tid]] = selv[tid];

#pragma unroll
    for (int t = 0; t < 3; ++t) {
        const int c = tid + t * 256;
        float accv = bdec[c];
#pragma unroll 8
        for (int j = 0; j < KSEL; ++j)
            accv = fmaf(selv[j], Wdec[(size_t)selp[j] * KIN + c], accv);
        xhat[(size_t)row * KIN + c] = accv;
    }
}

// ---------------------------------------------------------------------------
extern "C" void kernel_launch(void* const* d_in, const int* in_sizes, int n_in,
                              void* d_out, int out_size, void* d_ws, size_t ws_size,
                              hipStream_t stream) {
    const float* x    = (const float*)d_in[0];
    const float* Wenc = (const float*)d_in[1];
    const float* benc = (const float*)d_in[2];
    const float* Wdec = (const float*)d_in[3];
    const float* bdec = (const float*)d_in[4];

    float* xhat = (float*)d_out;                        // [8192, 768]
    float* z    = (float*)d_out + (size_t)MB * KIN;     // [8192, 16384]

    const size_t szA  = (size_t)MB * KIN * 2;           // 12.58 MB
    const size_t szB  = (size_t)NSAE * KIN * 2;         // 25.17 MB
    const size_t szWT = (size_t)NSAE * KIN * 4;         // 50.33 MB
    const size_t szWd = (size_t)NSAE * KIN * 2;         // 25.17 MB

    if (ws_size >= szA + szB + szWT + szWd) {
        unsigned short* Aws = (unsigned short*)d_ws;
        unsigned short* Bws = (unsigned short*)((char*)d_ws + szA);
        float*          WT  = (float*)((char*)d_ws + szA + szB);
        unsigned short* WdB = (unsigned short*)((char*)d_ws + szA + szB + szWT);
        unsigned short* preB = (unsigned short*)z;      // row-strided bf16 pre
        conv_x<<<dim3(MB * (KIN / 8) / 256), dim3(256), 0, stream>>>(x, bdec, Aws);
        transpose_wenc<<<dim3(NSAE / 32, KIN / 32), dim3(256), 0, stream>>>(Wenc, WT, Bws);
        conv_wdec<<<dim3((NSAE / 8) * (KIN / 256)), dim3(256), 0, stream>>>(Wdec, WdB);
        sae_encode_mfma<<<dim3(NSAE / 128, MB / 256), dim3(512), 0, stream>>>(
            Aws, Bws, benc, preB, NSAE * 2);
        sae_fused<<<dim3(MB), dim3(256), 0, stream>>>(
            x, WT, benc, bdec, WdB, xhat, z);
    } else if (ws_size >= szWT) {
        float* WT = (float*)d_ws;
        sae_encode_gemm<<<dim3(NSAE / BN, MB / BM), dim3(256), 0, stream>>>(
            x, Wenc, benc, bdec, z);
        transpose_wenc<<<dim3(NSAE / 32, KIN / 32), dim3(256), 0, stream>>>(Wenc, WT, nullptr);
        sae_topk_decode<true><<<dim3(MB), dim3(256), 0, stream>>>(
            z, x, WT, benc, Wdec, bdec, xhat);
    } else {
        sae_encode_gemm<<<dim3(NSAE / BN, MB / BM), dim3(256), 0, stream>>>(
            x, Wenc, benc, bdec, z);
        sae_topk_decode<false><<<dim3(MB), dim3(256), 0, stream>>>(
            z, x, Wenc, benc, Wdec, bdec, xhat);
    }
}

// Round 19
// 583.605 us; speedup vs baseline: 1.0862x; 1.0153x over previous
//
#include <hip/hip_runtime.h>
#include <cstdint>
#include <cstddef>

#define MB    8192
#define NSAE  16384
#define KIN   768
#define KSEL  32
#define NBIN  1024
#define BAND  8      // +/- band (bf16 ULP bins) around screened rank-32
#define UMAX  160    // uncertain-candidate capacity (typ ~25)
#define CMAX  40     // certain-in capacity (provably <= 31)
#define NCMAX 128    // legacy fallback kernels

#define BM  128
#define BN  128
#define BKK 16
#define APAD 132

#define EPAD 144     // epilogue LDS row stride in ushorts (128 + 16 pad)

typedef __attribute__((ext_vector_type(8))) short bfrag;
typedef __attribute__((ext_vector_type(4))) float ffrag;

__device__ __forceinline__ unsigned short f2bf(float f) {
    unsigned u = __float_as_uint(f);
    return (unsigned short)((u + 0x7FFFu + ((u >> 16) & 1u)) >> 16);
}

__device__ __forceinline__ void async_load16(const void* gsrc, void* ldsdst) {
    __builtin_amdgcn_global_load_lds(
        (const __attribute__((address_space(1))) unsigned int*)gsrc,
        (__attribute__((address_space(3))) unsigned int*)ldsdst,
        16, 0, 0);
}

// ---------------------------------------------------------------------------
// Prep A: Aws[m][k ^ ((m&7)*8)] = bf16(x[m][k] - bdec[k])   (swizzled bf16)
// ---------------------------------------------------------------------------
__global__ __launch_bounds__(256) void conv_x(
    const float* __restrict__ x, const float* __restrict__ bdec,
    unsigned short* __restrict__ Aws)
{
    const int t  = blockIdx.x * 256 + threadIdx.x;
    const int m  = t / (KIN / 8);
    const int k0 = (t % (KIN / 8)) * 8;
    const float4 v0 = *reinterpret_cast<const float4*>(&x[(size_t)m * KIN + k0]);
    const float4 v1 = *reinterpret_cast<const float4*>(&x[(size_t)m * KIN + k0 + 4]);
    const float4 b0 = *reinterpret_cast<const float4*>(&bdec[k0]);
    const float4 b1 = *reinterpret_cast<const float4*>(&bdec[k0 + 4]);
    uint4 o;
    o.x = (unsigned)f2bf(v0.x - b0.x) | ((unsigned)f2bf(v0.y - b0.y) << 16);
    o.y = (unsigned)f2bf(v0.z - b0.z) | ((unsigned)f2bf(v0.w - b0.w) << 16);
    o.z = (unsigned)f2bf(v1.x - b1.x) | ((unsigned)f2bf(v1.y - b1.y) << 16);
    o.w = (unsigned)f2bf(v1.z - b1.z) | ((unsigned)f2bf(v1.w - b1.w) << 16);
    *reinterpret_cast<uint4*>(&Aws[(size_t)m * KIN + (k0 ^ ((m & 7) * 8))]) = o;
}

// ---------------------------------------------------------------------------
// Prep B: WT[n][k] = W_enc[k][n] (fp32) and optionally swizzled bf16 Bws
// ---------------------------------------------------------------------------
__global__ __launch_bounds__(256) void transpose_wenc(
    const float* __restrict__ W, float* __restrict__ WT,
    unsigned short* __restrict__ Bws)
{
    __shared__ float t[32][33];
    const int bn = blockIdx.x * 32;
    const int bk = blockIdx.y * 32;
    const int lx = threadIdx.x & 31;
    const int ly = threadIdx.x >> 5;
#pragma unroll
    for (int r = 0; r < 4; ++r)
        t[ly + 8 * r][lx] = W[(size_t)(bk + ly + 8 * r) * NSAE + bn + lx];
    __syncthreads();
#pragma unroll
    for (int r = 0; r < 4; ++r) {
        const int n = bn + ly + 8 * r;
        const int k = bk + lx;
        const float v = t[lx][ly + 8 * r];
        WT[(size_t)n * KIN + k] = v;
        if (Bws) Bws[(size_t)n * KIN + (k ^ ((n & 7) * 8))] = f2bf(v);
    }
}

// ---------------------------------------------------------------------------
// Prep C: WdB = bf16(W_dec), same [NSAE][KIN] layout (halves decode traffic)
// ---------------------------------------------------------------------------
__global__ __launch_bounds__(256) void conv_wdec(
    const float* __restrict__ W, unsigned short* __restrict__ WB)
{
    const size_t t = (size_t)blockIdx.x * 256 + threadIdx.x;  // NSAE*KIN/8
    const float4 v0 = *reinterpret_cast<const float4*>(&W[t * 8]);
    const float4 v1 = *reinterpret_cast<const float4*>(&W[t * 8 + 4]);
    uint4 o;
    o.x = (unsigned)f2bf(v0.x) | ((unsigned)f2bf(v0.y) << 16);
    o.y = (unsigned)f2bf(v0.z) | ((unsigned)f2bf(v0.w) << 16);
    o.z = (unsigned)f2bf(v1.x) | ((unsigned)f2bf(v1.y) << 16);
    o.w = (unsigned)f2bf(v1.z) | ((unsigned)f2bf(v1.w) << 16);
    *reinterpret_cast<uint4*>(&WB[t * 8]) = o;
}

// ---------------------------------------------------------------------------
// Kernel 1: bf16 MFMA screening GEMM -> bf16 pre (row-strided).
// 256x128 block tile, 8 waves; vectorized LDS-restage epilogue (R18 form).
// ---------------------------------------------------------------------------
__global__ __launch_bounds__(512) void sae_encode_mfma(
    const unsigned short* __restrict__ Aws,
    const unsigned short* __restrict__ Bws,
    const float* __restrict__ benc,
    unsigned short* __restrict__ preB,
    int rstride)
{
    __shared__ __align__(16) unsigned short Sh[256 * 64 + 128 * 64]; // 48 KB
    unsigned short* Al = Sh;                // [256][64]
    unsigned short* Bl = Sh + 256 * 64;     // [128][64]

    const int tid = threadIdx.x;
    const int w   = tid >> 6;            // 0..7
    const int l   = tid & 63;
    const int wr  = (w >> 1) * 64;       // 0,64,128,192
    const int wc  = (w & 1) * 64;        // 0,64
    const int row0 = blockIdx.y * 256;
    const int col0 = blockIdx.x * 128;

    ffrag acc[4][4];
#pragma unroll
    for (int i = 0; i < 4; ++i)
#pragma unroll
        for (int j = 0; j < 4; ++j)
#pragma unroll
            for (int r = 0; r < 4; ++r) acc[i][j][r] = 0.0f;

    const int sra = w * 32 + (l >> 3);
    const int srb = w * 16 + (l >> 3);
    const int sb  = (l & 7) * 16;
    const char* Ag = (const char*)(Aws + (size_t)(row0 + sra) * KIN) + sb;
    const char* Bg = (const char*)(Bws + (size_t)(col0 + srb) * KIN) + sb;

    const int g = l >> 4;
    const int q = l & 15;

    for (int kt = 0; kt < KIN / 64; ++kt) {
#pragma unroll
        for (int i = 0; i < 4; ++i)
            async_load16(Ag + (size_t)i * 8 * (KIN * 2) + kt * 128,
                         &Al[(w * 32 + i * 8) * 64]);
#pragma unroll
        for (int i = 0; i < 2; ++i)
            async_load16(Bg + (size_t)i * 8 * (KIN * 2) + kt * 128,
                         &Bl[(w * 16 + i * 8) * 64]);
        __syncthreads();
#pragma unroll
        for (int kk = 0; kk < 2; ++kk) {
            bfrag af[4], bf[4];
#pragma unroll
            for (int mf = 0; mf < 4; ++mf) {
                const int m = wr + mf * 16 + q;
                af[mf] = *reinterpret_cast<const bfrag*>(
                    &Al[m * 64 + ((kk * 32 + g * 8) ^ ((m & 7) * 8))]);
            }
#pragma unroll
            for (int nf = 0; nf < 4; ++nf) {
                const int n = wc + nf * 16 + q;
                bf[nf] = *reinterpret_cast<const bfrag*>(
                    &Bl[n * 64 + ((kk * 32 + g * 8) ^ ((n & 7) * 8))]);
            }
#pragma unroll
            for (int mf = 0; mf < 4; ++mf)
#pragma unroll
                for (int nf = 0; nf < 4; ++nf)
                    acc[mf][nf] = __builtin_amdgcn_mfma_f32_16x16x32_bf16(
                        af[mf], bf[nf], acc[mf][nf], 0, 0, 0);
        }
        __syncthreads();
    }

    // ---- vectorized epilogue: two 128-row halves via LDS restage ----
    float be[4];
#pragma unroll
    for (int nf = 0; nf < 4; ++nf)
        be[nf] = benc[col0 + wc + nf * 16 + q];

#pragma unroll
    for (int h = 0; h < 2; ++h) {
        if ((w >> 2) == h) {
            const int lrb = (wr & 63) + ((w >> 1) & 1) * 64;  // wr - h*128
#pragma unroll
            for (int nf = 0; nf < 4; ++nf) {
                const int lc = wc + nf * 16 + q;
#pragma unroll
                for (int mf = 0; mf < 4; ++mf) {
                    const int lr0 = lrb + mf * 16 + g * 4;
#pragma unroll
                    for (int r = 0; r < 4; ++r)
                        Sh[(lr0 + r) * EPAD + lc] =
                            f2bf(fmaxf(acc[mf][nf][r] + be[nf], 0.0f));
                }
            }
        }
        __syncthreads();
#pragma unroll
        for (int i = 0; i < 4; ++i) {
            const int idx = i * 512 + tid;       // 0..2047
            const int r   = idx >> 4;            // 0..127
            const int c   = (idx & 15) * 8;      // 0..120
            *reinterpret_cast<uint4*>(
                &preB[(size_t)(row0 + h * 128 + r) * rstride + col0 + c]) =
                *reinterpret_cast<const uint4*>(&Sh[r * EPAD + c]);
        }
        __syncthreads();
    }
}

// ---------------------------------------------------------------------------
// Kernel 2: fused select+decode with certainty-band refinement.
// NEW: refine loads are float4 (4 lanes/cand, lane*16B + j*64B) with
// BOUNDED unroll (4) to avoid the R13 register cliff.
// ---------------------------------------------------------------------------
__global__ __launch_bounds__(256) void sae_fused(
    const float* __restrict__ x,
    const float* __restrict__ WT,        // [NSAE][KIN] fp32
    const float* __restrict__ benc,
    const float* __restrict__ bdec,
    const unsigned short* __restrict__ WdB,  // [NSAE][KIN] bf16
    float* __restrict__ xhat,            // [MB][KIN]
    float* __restrict__ z)               // [MB][NSAE]; first 32KB of row = preB
{
    const int row = blockIdx.x;
    const int tid = threadIdx.x;
    float* rp = z + (size_t)row * NSAE;
    const unsigned short* pp = (const unsigned short*)rp;

    __shared__ int      hist[NBIN];
    __shared__ int      s_v32;
    __shared__ int      s_cc;
    __shared__ int      s_uc;
    __shared__ int      cidx[CMAX];
    __shared__ float    cval[CMAX];
    __shared__ int      uidx[UMAX];
    __shared__ float    ukey[UMAX];
    __shared__ double   xsd[KIN];
    __shared__ float    selv[KSEL];
    __shared__ int      selp[KSEL];

    // ---- stage this row's bf16 pre into registers ----
    uint4 u4[8];
#pragma unroll
    for (int i = 0; i < 8; ++i)
        u4[i] = reinterpret_cast<const uint4*>(pp)[i * 256 + tid];

    for (int i = tid; i < NBIN; i += 256) hist[i] = 0;
    if (tid == 0) { s_cc = 0; s_uc = 0; s_v32 = -1; }
    if (tid < KSEL) { selv[tid] = 0.0f; selp[tid] = 0; }
    for (int i = tid; i < KIN; i += 256)
        xsd[i] = (double)x[(size_t)row * KIN + i] - (double)bdec[i];
    __syncthreads();

    // ---- exact bf16-resolution histogram of values >= 1.0 (0x3F80) ----
#pragma unroll
    for (int i = 0; i < 8; ++i) {
        const unsigned wv[4] = {u4[i].x, u4[i].y, u4[i].z, u4[i].w};
#pragma unroll
        for (int j = 0; j < 4; ++j) {
            const unsigned lo = wv[j] & 0xFFFFu;
            const unsigned hi = wv[j] >> 16;
            if (lo >= 0x3F80u) {
                int b = (int)(lo - 0x3F80u); if (b > NBIN - 1) b = NBIN - 1;
                atomicAdd(&hist[b], 1);
            }
            if (hi >= 0x3F80u) {
                int b = (int)(hi - 0x3F80u); if (b > NBIN - 1) b = NBIN - 1;
                atomicAdd(&hist[b], 1);
            }
        }
    }

    // ---- issue z-row zeroing (drains under the scan/refine) ----
    const float4 z4 = make_float4(0.0f, 0.0f, 0.0f, 0.0f);
#pragma unroll
    for (int i = 0; i < 16; ++i)
        reinterpret_cast<float4*>(rp)[i * 256 + tid] = z4;
    __syncthreads();

    // ---- wave 0: suffix-scan 1024 bins -> screened rank-32 bin ----
    if (tid < 64) {
        int hb[16]; int s16 = 0;
#pragma unroll
        for (int b = 0; b < 16; ++b) { hb[b] = hist[tid * 16 + b]; s16 += hb[b]; }
        int suf = s16;
#pragma unroll
        for (int off = 1; off < 64; off <<= 1) {
            const int v = __shfl_down(suf, off);
            if (tid + off < 64) suf += v;
        }
        const int tail  = suf - s16;
        const int total = __shfl(suf, 0);
        if (total >= KSEL && tail < KSEL && suf >= KSEL) {
            int cum = tail;
#pragma unroll
            for (int b = 15; b >= 0; --b) {
                cum += hb[b];
                if (cum >= KSEL) { s_v32 = tid * 16 + b; break; }
            }
        }
    }
    __syncthreads();

    const int v32 = s_v32;
    unsigned Tlo, Thi;
    if (v32 >= 3 * BAND) {
        Tlo = 0x3F80u + (unsigned)(v32 - BAND);
        Thi = 0x3F80u + (unsigned)(v32 + BAND);
    } else {
        Tlo = 0x3F80u;
        Thi = 0xFFFFu;
    }

    // ---- collect certain-in and uncertain candidates ----
#pragma unroll
    for (int i = 0; i < 8; ++i) {
        const unsigned wv[4] = {u4[i].x, u4[i].y, u4[i].z, u4[i].w};
#pragma unroll
        for (int j = 0; j < 4; ++j) {
            const int base = (i * 256 + tid) * 8 + j * 2;
            const unsigned bb[2] = {wv[j] & 0xFFFFu, wv[j] >> 16};
#pragma unroll
            for (int h = 0; h < 2; ++h) {
                const unsigned b = bb[h];
                if (b > Thi) {
                    const int s = atomicAdd(&s_cc, 1);
                    if (s < CMAX) {
                        cidx[s] = base + h;
                        cval[s] = __uint_as_float(b << 16);
                    }
                } else if (b >= Tlo) {
                    const int s = atomicAdd(&s_uc, 1);
                    if (s < UMAX) uidx[s] = base + h;
                }
            }
        }
    }
    __syncthreads();
    const int C = (s_cc < KSEL) ? s_cc : KSEL;
    const int U = (s_uc < UMAX) ? s_uc : UMAX;
    const int need = KSEL - C;

    // ---- fp64 refinement of uncertain -> fp32 keys.
    //      4 lanes/cand, float4 loads at lane*16B + j*64B (64B-contiguous
    //      per group); xsd reads cover banks 0..31 once per group and
    //      broadcast across groups. Bounded unroll keeps VGPR low (R13). ----
    for (int cnd = tid >> 2; cnd < U; cnd += 64) {
        const int lane = tid & 3;
        const int idx  = uidx[cnd];
        const float* wp = WT + (size_t)idx * KIN + lane * 4;
        double acc = 0.0;
#pragma unroll 4
        for (int j = 0; j < KIN / 16; ++j) {       // 48 float4 per lane
            const float4 wv = *reinterpret_cast<const float4*>(wp + j * 16);
            const int base = lane * 4 + j * 16;
            acc = fma(xsd[base + 0], (double)wv.x, acc);
            acc = fma(xsd[base + 1], (double)wv.y, acc);
            acc = fma(xsd[base + 2], (double)wv.z, acc);
            acc = fma(xsd[base + 3], (double)wv.w, acc);
        }
        acc += __shfl_down(acc, 2, 4);
        acc += __shfl_down(acc, 1, 4);
        if (lane == 0)
            ukey[cnd] = fmaxf((float)(acc + (double)benc[idx]), 0.0f);
    }
    __syncthreads();

    // ---- fill selection: certains first, then top-need uncertain ----
    if (tid < C) { selv[tid] = cval[tid]; selp[tid] = cidx[tid]; }
    if (tid < U) {
        const float v = ukey[tid];
        const int   p = uidx[tid];
        int rank = 0;
        for (int j = 0; j < U; ++j) {
            const float vj = ukey[j];
            const int   pj = uidx[j];
            if (vj > v || (vj == v && pj < p)) ++rank;
        }
        if (rank < need) { selv[C + rank] = v; selp[C + rank] = p; }
    }
    __syncthreads();   // drains z-zero stores block-wide too

    // ---- scatter selection into the zeroed z row ----
    if (tid < KSEL && selv[tid] != 0.0f) rp[selp[tid]] = selv[tid];

    // ---- sparse decode from bf16 Wdec: xhat = b_dec + sum_j v_j*Wdec[p_j] ----
    const unsigned* Wd32 = (const unsigned*)WdB;   // [NSAE][KIN/2] packed pairs
#pragma unroll
    for (int pass = 0; pass < 2; ++pass) {
        const int u = tid + pass * 256;            // column pair index
        if (u < KIN / 2) {
            float a0 = bdec[2 * u];
            float a1 = bdec[2 * u + 1];
#pragma unroll 8
            for (int j = 0; j < KSEL; ++j) {
                const unsigned w = Wd32[(size_t)selp[j] * (KIN / 2) + u];
                a0 = fmaf(selv[j], __uint_as_float(w << 16), a0);
                a1 = fmaf(selv[j], __uint_as_float(w & 0xFFFF0000u), a1);
            }
            float2 o; o.x = a0; o.y = a1;
            *reinterpret_cast<float2*>(&xhat[(size_t)row * KIN + 2 * u]) = o;
        }
    }
}

// ---------------------------------------------------------------------------
// Fallback kernels (fp32 pipeline, used only when workspace is small)
// ---------------------------------------------------------------------------
__global__ __launch_bounds__(256) void sae_encode_gemm(
    const float* __restrict__ x,
    const float* __restrict__ Wenc,
    const float* __restrict__ benc,
    const float* __restrict__ bdec,
    float* __restrict__ pre)
{
    __shared__ float As[BKK][APAD];
    __shared__ float Bs[BKK][BN];

    const int tid  = threadIdx.x;
    const int tx   = tid & 15;
    const int ty   = tid >> 4;
    const int col0 = blockIdx.x * BN;
    const int row0 = blockIdx.y * BM;

    const int ar = tid >> 2;
    const int ac = (tid & 3) << 2;
    const int br = tid >> 5;
    const int bc = (tid & 31) << 2;

    float acc[8][8];
#pragma unroll
    for (int i = 0; i < 8; ++i)
#pragma unroll
        for (int j = 0; j < 8; ++j) acc[i][j] = 0.0f;

    for (int kt = 0; kt < KIN; kt += BKK) {
        const float bd0 = bdec[kt + ac + 0];
        const float bd1 = bdec[kt + ac + 1];
        const float bd2 = bdec[kt + ac + 2];
        const float bd3 = bdec[kt + ac + 3];
#pragma unroll
        for (int h = 0; h < 2; ++h) {
            const int r = ar + h * 64;
            const float4 av = *reinterpret_cast<const float4*>(
                &x[(size_t)(row0 + r) * KIN + kt + ac]);
            As[ac + 0][r] = av.x - bd0;
            As[ac + 1][r] = av.y - bd1;
            As[ac + 2][r] = av.z - bd2;
            As[ac + 3][r] = av.w - bd3;
        }
#pragma unroll
        for (int h = 0; h < 2; ++h) {
            const int r = br + h * 8;
            *reinterpret_cast<float4*>(&Bs[r][bc]) =
                *reinterpret_cast<const float4*>(
                    &Wenc[(size_t)(kt + r) * NSAE + col0 + bc]);
        }
        __syncthreads();

#pragma unroll
        for (int k = 0; k < BKK; ++k) {
            float a[8], b[8];
            *reinterpret_cast<float4*>(&a[0]) =
                *reinterpret_cast<const float4*>(&As[k][ty * 4]);
            *reinterpret_cast<float4*>(&a[4]) =
                *reinterpret_cast<const float4*>(&As[k][64 + ty * 4]);
            *reinterpret_cast<float4*>(&b[0]) =
                *reinterpret_cast<const float4*>(&Bs[k][tx * 4]);
            *reinterpret_cast<float4*>(&b[4]) =
                *reinterpret_cast<const float4*>(&Bs[k][64 + tx * 4]);
#pragma unroll
            for (int i = 0; i < 8; ++i)
#pragma unroll
                for (int j = 0; j < 8; ++j)
                    acc[i][j] = fmaf(a[i], b[j], acc[i][j]);
        }
        __syncthreads();
    }

#pragma unroll
    for (int i = 0; i < 8; ++i) {
        const int gr = row0 + ((i & 3) + ty * 4) + ((i >> 2) * 64);
#pragma unroll
        for (int jg = 0; jg < 2; ++jg) {
            const int gc = col0 + tx * 4 + jg * 64;
            float4 v;
            v.x = fmaxf(acc[i][jg * 4 + 0] + benc[gc + 0], 0.0f);
            v.y = fmaxf(acc[i][jg * 4 + 1] + benc[gc + 1], 0.0f);
            v.z = fmaxf(acc[i][jg * 4 + 2] + benc[gc + 2], 0.0f);
            v.w = fmaxf(acc[i][jg * 4 + 3] + benc[gc + 3], 0.0f);
            *reinterpret_cast<float4*>(&pre[(size_t)gr * NSAE + gc]) = v;
        }
    }
}

template <bool TR>
__global__ __launch_bounds__(256) void sae_topk_decode(
    float* __restrict__ z,
    const float* __restrict__ x,
    const float* __restrict__ Wcol,
    const float* __restrict__ benc,
    const float* __restrict__ Wdec,
    const float* __restrict__ bdec,
    float* __restrict__ xhat)
{
    const int row = blockIdx.x;
    const int tid = threadIdx.x;
    float* rp = z + (size_t)row * NSAE;

    __shared__ int      hist[16];
    __shared__ unsigned s_pfx;
    __shared__ int      s_need;
    __shared__ int      s_nc;
    __shared__ int      candp[NCMAX];
    __shared__ float    candf[NCMAX];
    __shared__ double   xsd[KIN];
    __shared__ float    selv[KSEL];
    __shared__ int      selp[KSEL];

    uint4 e[16];
#pragma unroll
    for (int i = 0; i < 16; ++i)
        e[i] = *reinterpret_cast<const uint4*>(&rp[i * 1024 + tid * 4]);

    if (tid == 0) { s_pfx = 0u; s_need = 64; s_nc = 0; }
    if (tid < 16) hist[tid] = 0;
    __syncthreads();

    for (int shift = 28; shift >= 0; shift -= 4) {
        const unsigned pfx   = s_pfx;
        const unsigned maskd = (shift == 28) ? 0u : (0xFFFFFFFFu << (shift + 4));
        int cnt[16];
#pragma unroll
        for (int d = 0; d < 16; ++d) cnt[d] = 0;
#pragma unroll
        for (int i = 0; i < 16; ++i) {
            const unsigned uu[4] = {e[i].x, e[i].y, e[i].z, e[i].w};
#pragma unroll
            for (int j = 0; j < 4; ++j)
                if ((uu[j] & maskd) == pfx) ++cnt[(uu[j] >> shift) & 15];
        }
#pragma unroll
        for (int d = 0; d < 16; ++d)
            if (cnt[d]) atomicAdd(&hist[d], cnt[d]);
        __syncthreads();
        if (tid == 0) {
            int cum = 0, sel = 0;
            const int need = s_need;
            for (int d = 15; d >= 0; --d) {
                const int c = hist[d];
                cum += c;
                if (cum >= need) { sel = d; s_need = need - (cum - c); break; }
            }
            s_pfx = pfx | ((unsigned)sel << shift);
        }
        __syncthreads();
        if (tid < 16) hist[tid] = 0;
        __syncthreads();
    }
    const unsigned T = s_pfx;

#pragma unroll
    for (int i = 0; i < 16; ++i) {
        const unsigned uu[4] = {e[i].x, e[i].y, e[i].z, e[i].w};
#pragma unroll
        for (int j = 0; j < 4; ++j) {
            if (uu[j] >= T) {
                const int slot = atomicAdd(&s_nc, 1);
                if (slot < NCMAX) candp[slot] = i * 1024 + tid * 4 + j;
            }
        }
    }
    if (tid < NCMAX) candf[tid] = -1.0f;
    for (int i = tid; i < KIN; i += 256)
        xsd[i] = (double)x[(size_t)row * KIN + i] - (double)bdec[i];
    __syncthreads();
    const int nc = (s_nc < NCMAX) ? s_nc : NCMAX;

    for (int cnd = tid >> 2; cnd < nc; cnd += 64) {
        const int lane = tid & 3;
        const int idx  = candp[cnd];
        double acc = 0.0;
        if (TR) {
            const float* wp = Wcol + (size_t)idx * KIN + lane;
            for (int j = 0; j < KIN / 4; ++j)
                acc = fma(xsd[lane + j * 4], (double)wp[j * 4], acc);
        } else {
            const float* wp = Wcol + idx;
            for (int j = 0; j < KIN / 4; ++j)
                acc = fma(xsd[lane + j * 4],
                          (double)wp[(size_t)(lane + j * 4) * NSAE], acc);
        }
        acc += __shfl_down(acc, 2, 4);
        acc += __shfl_down(acc, 1, 4);
        if (lane == 0)
            candf[cnd] = fmaxf((float)(acc + (double)benc[idx]), 0.0f);
    }
    __syncthreads();

    if (tid < KSEL) { selv[tid] = 0.0f; selp[tid] = 0; }
    __syncthreads();

    if (tid < nc) {
        const float v = candf[tid];
        const int   p = candp[tid];
        int rank = 0;
        for (int j = 0; j < nc; ++j) {
            const float vj = candf[j];
            const int   pj = candp[j];
            if (vj > v || (vj == v && pj < p)) ++rank;
        }
        if (rank < KSEL) { selv[rank] = v; selp[rank] = p; }
    }
    __syncthreads();

    const float4 zv4 = make_float4(0.0f, 0.0f, 0.0f, 0.0f);
#pragma unroll
    for (int i = 0; i < 16; ++i)
        *reinterpret_cast<float4*>(&rp[i * 1024 + tid * 4]) = zv4;
    __syncthreads();
    if (tid < KSEL && selv[tid] != 0.0f) rp[selp[tid]] = selv[tid];

#pragma unroll
    for (int t = 0; t < 3; ++t) {
        const int c = tid + t * 256;
        float accv = bdec[c];
#pragma unroll 8
        for (int j = 0; j < KSEL; ++j)
            accv = fmaf(selv[j], Wdec[(size_t)selp[j] * KIN + c], accv);
        xhat[(size_t)row * KIN + c] = accv;
    }
}

// ---------------------------------------------------------------------------
extern "C" void kernel_launch(void* const* d_in, const int* in_sizes, int n_in,
                              void* d_out, int out_size, void* d_ws, size_t ws_size,
                              hipStream_t stream) {
    const float* x    = (const float*)d_in[0];
    const float* Wenc = (const float*)d_in[1];
    const float* benc = (const float*)d_in[2];
    const float* Wdec = (const float*)d_in[3];
    const float* bdec = (const float*)d_in[4];

    float* xhat = (float*)d_out;                        // [8192, 768]
    float* z    = (float*)d_out + (size_t)MB * KIN;     // [8192, 16384]

    const size_t szA  = (size_t)MB * KIN * 2;           // 12.58 MB
    const size_t szB  = (size_t)NSAE * KIN * 2;         // 25.17 MB
    const size_t szWT = (size_t)NSAE * KIN * 4;         // 50.33 MB
    const size_t szWd = (size_t)NSAE * KIN * 2;         // 25.17 MB

    if (ws_size >= szA + szB + szWT + szWd) {
        unsigned short* Aws = (unsigned short*)d_ws;
        unsigned short* Bws = (unsigned short*)((char*)d_ws + szA);
        float*          WT  = (float*)((char*)d_ws + szA + szB);
        unsigned short* WdB = (unsigned short*)((char*)d_ws + szA + szB + szWT);
        unsigned short* preB = (unsigned short*)z;      // row-strided bf16 pre
        conv_x<<<dim3(MB * (KIN / 8) / 256), dim3(256), 0, stream>>>(x, bdec, Aws);
        transpose_wenc<<<dim3(NSAE / 32, KIN / 32), dim3(256), 0, stream>>>(Wenc, WT, Bws);
        conv_wdec<<<dim3((NSAE / 8) * (KIN / 256)), dim3(256), 0, stream>>>(Wdec, WdB);
        sae_encode_mfma<<<dim3(NSAE / 128, MB / 256), dim3(512), 0, stream>>>(
            Aws, Bws, benc, preB, NSAE * 2);
        sae_fused<<<dim3(MB), dim3(256), 0, stream>>>(
            x, WT, benc, bdec, WdB, xhat, z);
    } else if (ws_size >= szWT) {
        float* WT = (float*)d_ws;
        sae_encode_gemm<<<dim3(NSAE / BN, MB / BM), dim3(256), 0, stream>>>(
            x, Wenc, benc, bdec, z);
        transpose_wenc<<<dim3(NSAE / 32, KIN / 32), dim3(256), 0, stream>>>(Wenc, WT, nullptr);
        sae_topk_decode<true><<<dim3(MB), dim3(256), 0, stream>>>(
            z, x, WT, benc, Wdec, bdec, xhat);
    } else {
        sae_encode_gemm<<<dim3(NSAE / BN, MB / BM), dim3(256), 0, stream>>>(
            x, Wenc, benc, bdec, z);
        sae_topk_decode<false><<<dim3(MB), dim3(256), 0, stream>>>(
            z, x, Wenc, benc, Wdec, bdec, xhat);
    }
}

// Round 20
// 567.672 us; speedup vs baseline: 1.1167x; 1.0281x over previous
//
#include <hip/hip_runtime.h>
#include <cstdint>
#include <cstddef>

#define MB    8192
#define NSAE  16384
#define KIN   768
#define KSEL  32
#define NBIN  1024
#define BAND  8      // +/- band (bf16 ULP bins) around screened rank-32
#define UMAX  160    // uncertain-candidate capacity (typ ~25)
#define CMAX  40     // certain-in capacity (provably <= 31)
#define NCMAX 128    // legacy fallback kernels

#define BM  128
#define BN  128
#define BKK 16
#define APAD 132

#define EPAD 144     // epilogue LDS row stride in ushorts (128 + 16 pad)

typedef __attribute__((ext_vector_type(8))) short bfrag;
typedef __attribute__((ext_vector_type(4))) float ffrag;

__device__ __forceinline__ unsigned short f2bf(float f) {
    unsigned u = __float_as_uint(f);
    return (unsigned short)((u + 0x7FFFu + ((u >> 16) & 1u)) >> 16);
}

__device__ __forceinline__ void async_load16(const void* gsrc, void* ldsdst) {
    __builtin_amdgcn_global_load_lds(
        (const __attribute__((address_space(1))) unsigned int*)gsrc,
        (__attribute__((address_space(3))) unsigned int*)ldsdst,
        16, 0, 0);
}

// ---------------------------------------------------------------------------
// Prep A: Aws[m][k ^ ((m&7)*8)] = bf16(x[m][k] - bdec[k])   (swizzled bf16)
// ---------------------------------------------------------------------------
__global__ __launch_bounds__(256) void conv_x(
    const float* __restrict__ x, const float* __restrict__ bdec,
    unsigned short* __restrict__ Aws)
{
    const int t  = blockIdx.x * 256 + threadIdx.x;
    const int m  = t / (KIN / 8);
    const int k0 = (t % (KIN / 8)) * 8;
    const float4 v0 = *reinterpret_cast<const float4*>(&x[(size_t)m * KIN + k0]);
    const float4 v1 = *reinterpret_cast<const float4*>(&x[(size_t)m * KIN + k0 + 4]);
    const float4 b0 = *reinterpret_cast<const float4*>(&bdec[k0]);
    const float4 b1 = *reinterpret_cast<const float4*>(&bdec[k0 + 4]);
    uint4 o;
    o.x = (unsigned)f2bf(v0.x - b0.x) | ((unsigned)f2bf(v0.y - b0.y) << 16);
    o.y = (unsigned)f2bf(v0.z - b0.z) | ((unsigned)f2bf(v0.w - b0.w) << 16);
    o.z = (unsigned)f2bf(v1.x - b1.x) | ((unsigned)f2bf(v1.y - b1.y) << 16);
    o.w = (unsigned)f2bf(v1.z - b1.z) | ((unsigned)f2bf(v1.w - b1.w) << 16);
    *reinterpret_cast<uint4*>(&Aws[(size_t)m * KIN + (k0 ^ ((m & 7) * 8))]) = o;
}

// ---------------------------------------------------------------------------
// Prep B: WT[n][k] = W_enc[k][n] (fp32) and optionally swizzled bf16 Bws
// ---------------------------------------------------------------------------
__global__ __launch_bounds__(256) void transpose_wenc(
    const float* __restrict__ W, float* __restrict__ WT,
    unsigned short* __restrict__ Bws)
{
    __shared__ float t[32][33];
    const int bn = blockIdx.x * 32;
    const int bk = blockIdx.y * 32;
    const int lx = threadIdx.x & 31;
    const int ly = threadIdx.x >> 5;
#pragma unroll
    for (int r = 0; r < 4; ++r)
        t[ly + 8 * r][lx] = W[(size_t)(bk + ly + 8 * r) * NSAE + bn + lx];
    __syncthreads();
#pragma unroll
    for (int r = 0; r < 4; ++r) {
        const int n = bn + ly + 8 * r;
        const int k = bk + lx;
        const float v = t[lx][ly + 8 * r];
        WT[(size_t)n * KIN + k] = v;
        if (Bws) Bws[(size_t)n * KIN + (k ^ ((n & 7) * 8))] = f2bf(v);
    }
}

// ---------------------------------------------------------------------------
// Prep C: WdB = bf16(W_dec), same [NSAE][KIN] layout (halves decode traffic)
// ---------------------------------------------------------------------------
__global__ __launch_bounds__(256) void conv_wdec(
    const float* __restrict__ W, unsigned short* __restrict__ WB)
{
    const size_t t = (size_t)blockIdx.x * 256 + threadIdx.x;  // NSAE*KIN/8
    const float4 v0 = *reinterpret_cast<const float4*>(&W[t * 8]);
    const float4 v1 = *reinterpret_cast<const float4*>(&W[t * 8 + 4]);
    uint4 o;
    o.x = (unsigned)f2bf(v0.x) | ((unsigned)f2bf(v0.y) << 16);
    o.y = (unsigned)f2bf(v0.z) | ((unsigned)f2bf(v0.w) << 16);
    o.z = (unsigned)f2bf(v1.x) | ((unsigned)f2bf(v1.y) << 16);
    o.w = (unsigned)f2bf(v1.z) | ((unsigned)f2bf(v1.w) << 16);
    *reinterpret_cast<uint4*>(&WB[t * 8]) = o;
}

// ---------------------------------------------------------------------------
// Kernel 1: bf16 MFMA screening GEMM -> bf16 pre (row-strided).
// 256x128 block tile, 8 waves; vectorized LDS-restage epilogue (R18 form).
// NEW (R20): grid axes swapped -- blockIdx.x = ROW tile (fastest), so 32
// consecutive blocks share one 196KB B panel and their A slices (12.6MB
// total, ~1.6MB/XCD) stay L2-resident -> staging drains at L2 latency.
// ---------------------------------------------------------------------------
__global__ __launch_bounds__(512) void sae_encode_mfma(
    const unsigned short* __restrict__ Aws,
    const unsigned short* __restrict__ Bws,
    const float* __restrict__ benc,
    unsigned short* __restrict__ preB,
    int rstride)
{
    __shared__ __align__(16) unsigned short Sh[256 * 64 + 128 * 64]; // 48 KB
    unsigned short* Al = Sh;                // [256][64]
    unsigned short* Bl = Sh + 256 * 64;     // [128][64]

    const int tid = threadIdx.x;
    const int w   = tid >> 6;            // 0..7
    const int l   = tid & 63;
    const int wr  = (w >> 1) * 64;       // 0,64,128,192
    const int wc  = (w & 1) * 64;        // 0,64
    const int row0 = blockIdx.x * 256;   // ROW fastest (swapped)
    const int col0 = blockIdx.y * 128;

    ffrag acc[4][4];
#pragma unroll
    for (int i = 0; i < 4; ++i)
#pragma unroll
        for (int j = 0; j < 4; ++j)
#pragma unroll
            for (int r = 0; r < 4; ++r) acc[i][j][r] = 0.0f;

    const int sra = w * 32 + (l >> 3);
    const int srb = w * 16 + (l >> 3);
    const int sb  = (l & 7) * 16;
    const char* Ag = (const char*)(Aws + (size_t)(row0 + sra) * KIN) + sb;
    const char* Bg = (const char*)(Bws + (size_t)(col0 + srb) * KIN) + sb;

    const int g = l >> 4;
    const int q = l & 15;

    for (int kt = 0; kt < KIN / 64; ++kt) {
#pragma unroll
        for (int i = 0; i < 4; ++i)
            async_load16(Ag + (size_t)i * 8 * (KIN * 2) + kt * 128,
                         &Al[(w * 32 + i * 8) * 64]);
#pragma unroll
        for (int i = 0; i < 2; ++i)
            async_load16(Bg + (size_t)i * 8 * (KIN * 2) + kt * 128,
                         &Bl[(w * 16 + i * 8) * 64]);
        __syncthreads();
#pragma unroll
        for (int kk = 0; kk < 2; ++kk) {
            bfrag af[4], bf[4];
#pragma unroll
            for (int mf = 0; mf < 4; ++mf) {
                const int m = wr + mf * 16 + q;
                af[mf] = *reinterpret_cast<const bfrag*>(
                    &Al[m * 64 + ((kk * 32 + g * 8) ^ ((m & 7) * 8))]);
            }
#pragma unroll
            for (int nf = 0; nf < 4; ++nf) {
                const int n = wc + nf * 16 + q;
                bf[nf] = *reinterpret_cast<const bfrag*>(
                    &Bl[n * 64 + ((kk * 32 + g * 8) ^ ((n & 7) * 8))]);
            }
#pragma unroll
            for (int mf = 0; mf < 4; ++mf)
#pragma unroll
                for (int nf = 0; nf < 4; ++nf)
                    acc[mf][nf] = __builtin_amdgcn_mfma_f32_16x16x32_bf16(
                        af[mf], bf[nf], acc[mf][nf], 0, 0, 0);
        }
        __syncthreads();
    }

    // ---- vectorized epilogue: two 128-row halves via LDS restage ----
    float be[4];
#pragma unroll
    for (int nf = 0; nf < 4; ++nf)
        be[nf] = benc[col0 + wc + nf * 16 + q];

#pragma unroll
    for (int h = 0; h < 2; ++h) {
        if ((w >> 2) == h) {
            const int lrb = (wr & 63) + ((w >> 1) & 1) * 64;  // wr - h*128
#pragma unroll
            for (int nf = 0; nf < 4; ++nf) {
                const int lc = wc + nf * 16 + q;
#pragma unroll
                for (int mf = 0; mf < 4; ++mf) {
                    const int lr0 = lrb + mf * 16 + g * 4;
#pragma unroll
                    for (int r = 0; r < 4; ++r)
                        Sh[(lr0 + r) * EPAD + lc] =
                            f2bf(fmaxf(acc[mf][nf][r] + be[nf], 0.0f));
                }
            }
        }
        __syncthreads();
#pragma unroll
        for (int i = 0; i < 4; ++i) {
            const int idx = i * 512 + tid;       // 0..2047
            const int r   = idx >> 4;            // 0..127
            const int c   = (idx & 15) * 8;      // 0..120
            *reinterpret_cast<uint4*>(
                &preB[(size_t)(row0 + h * 128 + r) * rstride + col0 + c]) =
                *reinterpret_cast<const uint4*>(&Sh[r * EPAD + c]);
        }
        __syncthreads();
    }
}

// ---------------------------------------------------------------------------
// Kernel 2: fused select+decode with certainty-band refinement (R19 form).
// ---------------------------------------------------------------------------
__global__ __launch_bounds__(256) void sae_fused(
    const float* __restrict__ x,
    const float* __restrict__ WT,        // [NSAE][KIN] fp32
    const float* __restrict__ benc,
    const float* __restrict__ bdec,
    const unsigned short* __restrict__ WdB,  // [NSAE][KIN] bf16
    float* __restrict__ xhat,            // [MB][KIN]
    float* __restrict__ z)               // [MB][NSAE]; first 32KB of row = preB
{
    const int row = blockIdx.x;
    const int tid = threadIdx.x;
    float* rp = z + (size_t)row * NSAE;
    const unsigned short* pp = (const unsigned short*)rp;

    __shared__ int      hist[NBIN];
    __shared__ int      s_v32;
    __shared__ int      s_cc;
    __shared__ int      s_uc;
    __shared__ int      cidx[CMAX];
    __shared__ float    cval[CMAX];
    __shared__ int      uidx[UMAX];
    __shared__ float    ukey[UMAX];
    __shared__ double   xsd[KIN];
    __shared__ float    selv[KSEL];
    __shared__ int      selp[KSEL];

    // ---- stage this row's bf16 pre into registers ----
    uint4 u4[8];
#pragma unroll
    for (int i = 0; i < 8; ++i)
        u4[i] = reinterpret_cast<const uint4*>(pp)[i * 256 + tid];

    for (int i = tid; i < NBIN; i += 256) hist[i] = 0;
    if (tid == 0) { s_cc = 0; s_uc = 0; s_v32 = -1; }
    if (tid < KSEL) { selv[tid] = 0.0f; selp[tid] = 0; }
    for (int i = tid; i < KIN; i += 256)
        xsd[i] = (double)x[(size_t)row * KIN + i] - (double)bdec[i];
    __syncthreads();

    // ---- exact bf16-resolution histogram of values >= 1.0 (0x3F80) ----
#pragma unroll
    for (int i = 0; i < 8; ++i) {
        const unsigned wv[4] = {u4[i].x, u4[i].y, u4[i].z, u4[i].w};
#pragma unroll
        for (int j = 0; j < 4; ++j) {
            const unsigned lo = wv[j] & 0xFFFFu;
            const unsigned hi = wv[j] >> 16;
            if (lo >= 0x3F80u) {
                int b = (int)(lo - 0x3F80u); if (b > NBIN - 1) b = NBIN - 1;
                atomicAdd(&hist[b], 1);
            }
            if (hi >= 0x3F80u) {
                int b = (int)(hi - 0x3F80u); if (b > NBIN - 1) b = NBIN - 1;
                atomicAdd(&hist[b], 1);
            }
        }
    }

    // ---- issue z-row zeroing (drains under the scan/refine) ----
    const float4 z4 = make_float4(0.0f, 0.0f, 0.0f, 0.0f);
#pragma unroll
    for (int i = 0; i < 16; ++i)
        reinterpret_cast<float4*>(rp)[i * 256 + tid] = z4;
    __syncthreads();

    // ---- wave 0: suffix-scan 1024 bins -> screened rank-32 bin ----
    if (tid < 64) {
        int hb[16]; int s16 = 0;
#pragma unroll
        for (int b = 0; b < 16; ++b) { hb[b] = hist[tid * 16 + b]; s16 += hb[b]; }
        int suf = s16;
#pragma unroll
        for (int off = 1; off < 64; off <<= 1) {
            const int v = __shfl_down(suf, off);
            if (tid + off < 64) suf += v;
        }
        const int tail  = suf - s16;
        const int total = __shfl(suf, 0);
        if (total >= KSEL && tail < KSEL && suf >= KSEL) {
            int cum = tail;
#pragma unroll
            for (int b = 15; b >= 0; --b) {
                cum += hb[b];
                if (cum >= KSEL) { s_v32 = tid * 16 + b; break; }
            }
        }
    }
    __syncthreads();

    const int v32 = s_v32;
    unsigned Tlo, Thi;
    if (v32 >= 3 * BAND) {
        Tlo = 0x3F80u + (unsigned)(v32 - BAND);
        Thi = 0x3F80u + (unsigned)(v32 + BAND);
    } else {
        Tlo = 0x3F80u;
        Thi = 0xFFFFu;
    }

    // ---- collect certain-in and uncertain candidates ----
#pragma unroll
    for (int i = 0; i < 8; ++i) {
        const unsigned wv[4] = {u4[i].x, u4[i].y, u4[i].z, u4[i].w};
#pragma unroll
        for (int j = 0; j < 4; ++j) {
            const int base = (i * 256 + tid) * 8 + j * 2;
            const unsigned bb[2] = {wv[j] & 0xFFFFu, wv[j] >> 16};
#pragma unroll
            for (int h = 0; h < 2; ++h) {
                const unsigned b = bb[h];
                if (b > Thi) {
                    const int s = atomicAdd(&s_cc, 1);
                    if (s < CMAX) {
                        cidx[s] = base + h;
                        cval[s] = __uint_as_float(b << 16);
                    }
                } else if (b >= Tlo) {
                    const int s = atomicAdd(&s_uc, 1);
                    if (s < UMAX) uidx[s] = base + h;
                }
            }
        }
    }
    __syncthreads();
    const int C = (s_cc < KSEL) ? s_cc : KSEL;
    const int U = (s_uc < UMAX) ? s_uc : UMAX;
    const int need = KSEL - C;

    // ---- fp64 refinement of uncertain -> fp32 keys (bounded-unroll float4) ----
    for (int cnd = tid >> 2; cnd < U; cnd += 64) {
        const int lane = tid & 3;
        const int idx  = uidx[cnd];
        const float* wp = WT + (size_t)idx * KIN + lane * 4;
        double acc = 0.0;
#pragma unroll 4
        for (int j = 0; j < KIN / 16; ++j) {       // 48 float4 per lane
            const float4 wv = *reinterpret_cast<const float4*>(wp + j * 16);
            const int base = lane * 4 + j * 16;
            acc = fma(xsd[base + 0], (double)wv.x, acc);
            acc = fma(xsd[base + 1], (double)wv.y, acc);
            acc = fma(xsd[base + 2], (double)wv.z, acc);
            acc = fma(xsd[base + 3], (double)wv.w, acc);
        }
        acc += __shfl_down(acc, 2, 4);
        acc += __shfl_down(acc, 1, 4);
        if (lane == 0)
            ukey[cnd] = fmaxf((float)(acc + (double)benc[idx]), 0.0f);
    }
    __syncthreads();

    // ---- fill selection: certains first, then top-need uncertain ----
    if (tid < C) { selv[tid] = cval[tid]; selp[tid] = cidx[tid]; }
    if (tid < U) {
        const float v = ukey[tid];
        const int   p = uidx[tid];
        int rank = 0;
        for (int j = 0; j < U; ++j) {
            const float vj = ukey[j];
            const int   pj = uidx[j];
            if (vj > v || (vj == v && pj < p)) ++rank;
        }
        if (rank < need) { selv[C + rank] = v; selp[C + rank] = p; }
    }
    __syncthreads();   // drains z-zero stores block-wide too

    // ---- scatter selection into the zeroed z row ----
    if (tid < KSEL && selv[tid] != 0.0f) rp[selp[tid]] = selv[tid];

    // ---- sparse decode from bf16 Wdec: xhat = b_dec + sum_j v_j*Wdec[p_j] ----
    const unsigned* Wd32 = (const unsigned*)WdB;   // [NSAE][KIN/2] packed pairs
#pragma unroll
    for (int pass = 0; pass < 2; ++pass) {
        const int u = tid + pass * 256;            // column pair index
        if (u < KIN / 2) {
            float a0 = bdec[2 * u];
            float a1 = bdec[2 * u + 1];
#pragma unroll 8
            for (int j = 0; j < KSEL; ++j) {
                const unsigned w = Wd32[(size_t)selp[j] * (KIN / 2) + u];
                a0 = fmaf(selv[j], __uint_as_float(w << 16), a0);
                a1 = fmaf(selv[j], __uint_as_float(w & 0xFFFF0000u), a1);
            }
            float2 o; o.x = a0; o.y = a1;
            *reinterpret_cast<float2*>(&xhat[(size_t)row * KIN + 2 * u]) = o;
        }
    }
}

// ---------------------------------------------------------------------------
// Fallback kernels (fp32 pipeline, used only when workspace is small)
// ---------------------------------------------------------------------------
__global__ __launch_bounds__(256) void sae_encode_gemm(
    const float* __restrict__ x,
    const float* __restrict__ Wenc,
    const float* __restrict__ benc,
    const float* __restrict__ bdec,
    float* __restrict__ pre)
{
    __shared__ float As[BKK][APAD];
    __shared__ float Bs[BKK][BN];

    const int tid  = threadIdx.x;
    const int tx   = tid & 15;
    const int ty   = tid >> 4;
    const int col0 = blockIdx.x * BN;
    const int row0 = blockIdx.y * BM;

    const int ar = tid >> 2;
    const int ac = (tid & 3) << 2;
    const int br = tid >> 5;
    const int bc = (tid & 31) << 2;

    float acc[8][8];
#pragma unroll
    for (int i = 0; i < 8; ++i)
#pragma unroll
        for (int j = 0; j < 8; ++j) acc[i][j] = 0.0f;

    for (int kt = 0; kt < KIN; kt += BKK) {
        const float bd0 = bdec[kt + ac + 0];
        const float bd1 = bdec[kt + ac + 1];
        const float bd2 = bdec[kt + ac + 2];
        const float bd3 = bdec[kt + ac + 3];
#pragma unroll
        for (int h = 0; h < 2; ++h) {
            const int r = ar + h * 64;
            const float4 av = *reinterpret_cast<const float4*>(
                &x[(size_t)(row0 + r) * KIN + kt + ac]);
            As[ac + 0][r] = av.x - bd0;
            As[ac + 1][r] = av.y - bd1;
            As[ac + 2][r] = av.z - bd2;
            As[ac + 3][r] = av.w - bd3;
        }
#pragma unroll
        for (int h = 0; h < 2; ++h) {
            const int r = br + h * 8;
            *reinterpret_cast<float4*>(&Bs[r][bc]) =
                *reinterpret_cast<const float4*>(
                    &Wenc[(size_t)(kt + r) * NSAE + col0 + bc]);
        }
        __syncthreads();

#pragma unroll
        for (int k = 0; k < BKK; ++k) {
            float a[8], b[8];
            *reinterpret_cast<float4*>(&a[0]) =
                *reinterpret_cast<const float4*>(&As[k][ty * 4]);
            *reinterpret_cast<float4*>(&a[4]) =
                *reinterpret_cast<const float4*>(&As[k][64 + ty * 4]);
            *reinterpret_cast<float4*>(&b[0]) =
                *reinterpret_cast<const float4*>(&Bs[k][tx * 4]);
            *reinterpret_cast<float4*>(&b[4]) =
                *reinterpret_cast<const float4*>(&Bs[k][64 + tx * 4]);
#pragma unroll
            for (int i = 0; i < 8; ++i)
#pragma unroll
                for (int j = 0; j < 8; ++j)
                    acc[i][j] = fmaf(a[i], b[j], acc[i][j]);
        }
        __syncthreads();
    }

#pragma unroll
    for (int i = 0; i < 8; ++i) {
        const int gr = row0 + ((i & 3) + ty * 4) + ((i >> 2) * 64);
#pragma unroll
        for (int jg = 0; jg < 2; ++jg) {
            const int gc = col0 + tx * 4 + jg * 64;
            float4 v;
            v.x = fmaxf(acc[i][jg * 4 + 0] + benc[gc + 0], 0.0f);
            v.y = fmaxf(acc[i][jg * 4 + 1] + benc[gc + 1], 0.0f);
            v.z = fmaxf(acc[i][jg * 4 + 2] + benc[gc + 2], 0.0f);
            v.w = fmaxf(acc[i][jg * 4 + 3] + benc[gc + 3], 0.0f);
            *reinterpret_cast<float4*>(&pre[(size_t)gr * NSAE + gc]) = v;
        }
    }
}

template <bool TR>
__global__ __launch_bounds__(256) void sae_topk_decode(
    float* __restrict__ z,
    const float* __restrict__ x,
    const float* __restrict__ Wcol,
    const float* __restrict__ benc,
    const float* __restrict__ Wdec,
    const float* __restrict__ bdec,
    float* __restrict__ xhat)
{
    const int row = blockIdx.x;
    const int tid = threadIdx.x;
    float* rp = z + (size_t)row * NSAE;

    __shared__ int      hist[16];
    __shared__ unsigned s_pfx;
    __shared__ int      s_need;
    __shared__ int      s_nc;
    __shared__ int      candp[NCMAX];
    __shared__ float    candf[NCMAX];
    __shared__ double   xsd[KIN];
    __shared__ float    selv[KSEL];
    __shared__ int      selp[KSEL];

    uint4 e[16];
#pragma unroll
    for (int i = 0; i < 16; ++i)
        e[i] = *reinterpret_cast<const uint4*>(&rp[i * 1024 + tid * 4]);

    if (tid == 0) { s_pfx = 0u; s_need = 64; s_nc = 0; }
    if (tid < 16) hist[tid] = 0;
    __syncthreads();

    for (int shift = 28; shift >= 0; shift -= 4) {
        const unsigned pfx   = s_pfx;
        const unsigned maskd = (shift == 28) ? 0u : (0xFFFFFFFFu << (shift + 4));
        int cnt[16];
#pragma unroll
        for (int d = 0; d < 16; ++d) cnt[d] = 0;
#pragma unroll
        for (int i = 0; i < 16; ++i) {
            const unsigned uu[4] = {e[i].x, e[i].y, e[i].z, e[i].w};
#pragma unroll
            for (int j = 0; j < 4; ++j)
                if ((uu[j] & maskd) == pfx) ++cnt[(uu[j] >> shift) & 15];
        }
#pragma unroll
        for (int d = 0; d < 16; ++d)
            if (cnt[d]) atomicAdd(&hist[d], cnt[d]);
        __syncthreads();
        if (tid == 0) {
            int cum = 0, sel = 0;
            const int need = s_need;
            for (int d = 15; d >= 0; --d) {
                const int c = hist[d];
                cum += c;
                if (cum >= need) { sel = d; s_need = need - (cum - c); break; }
            }
            s_pfx = pfx | ((unsigned)sel << shift);
        }
        __syncthreads();
        if (tid < 16) hist[tid] = 0;
        __syncthreads();
    }
    const unsigned T = s_pfx;

#pragma unroll
    for (int i = 0; i < 16; ++i) {
        const unsigned uu[4] = {e[i].x, e[i].y, e[i].z, e[i].w};
#pragma unroll
        for (int j = 0; j < 4; ++j) {
            if (uu[j] >= T) {
                const int slot = atomicAdd(&s_nc, 1);
                if (slot < NCMAX) candp[slot] = i * 1024 + tid * 4 + j;
            }
        }
    }
    if (tid < NCMAX) candf[tid] = -1.0f;
    for (int i = tid; i < KIN; i += 256)
        xsd[i] = (double)x[(size_t)row * KIN + i] - (double)bdec[i];
    __syncthreads();
    const int nc = (s_nc < NCMAX) ? s_nc : NCMAX;

    for (int cnd = tid >> 2; cnd < nc; cnd += 64) {
        const int lane = tid & 3;
        const int idx  = candp[cnd];
        double acc = 0.0;
        if (TR) {
            const float* wp = Wcol + (size_t)idx * KIN + lane;
            for (int j = 0; j < KIN / 4; ++j)
                acc = fma(xsd[lane + j * 4], (double)wp[j * 4], acc);
        } else {
            const float* wp = Wcol + idx;
            for (int j = 0; j < KIN / 4; ++j)
                acc = fma(xsd[lane + j * 4],
                          (double)wp[(size_t)(lane + j * 4) * NSAE], acc);
        }
        acc += __shfl_down(acc, 2, 4);
        acc += __shfl_down(acc, 1, 4);
        if (lane == 0)
            candf[cnd] = fmaxf((float)(acc + (double)benc[idx]), 0.0f);
    }
    __syncthreads();

    if (tid < KSEL) { selv[tid] = 0.0f; selp[tid] = 0; }
    __syncthreads();

    if (tid < nc) {
        const float v = candf[tid];
        const int   p = candp[tid];
        int rank = 0;
        for (int j = 0; j < nc; ++j) {
            const float vj = candf[j];
            const int   pj = candp[j];
            if (vj > v || (vj == v && pj < p)) ++rank;
        }
        if (rank < KSEL) { selv[rank] = v; selp[rank] = p; }
    }
    __syncthreads();

    const float4 zv4 = make_float4(0.0f, 0.0f, 0.0f, 0.0f);
#pragma unroll
    for (int i = 0; i < 16; ++i)
        *reinterpret_cast<float4*>(&rp[i * 1024 + tid * 4]) = zv4;
    __syncthreads();
    if (tid < KSEL && selv[tid] != 0.0f) rp[selp[tid]] = selv[tid];

#pragma unroll
    for (int t = 0; t < 3; ++t) {
        const int c = tid + t * 256;
        float accv = bdec[c];
#pragma unroll 8
        for (int j = 0; j < KSEL; ++j)
            accv = fmaf(selv[j], Wdec[(size_t)selp[j] * KIN + c], accv);
        xhat[(size_t)row * KIN + c] = accv;
    }
}

// ---------------------------------------------------------------------------
extern "C" void kernel_launch(void* const* d_in, const int* in_sizes, int n_in,
                              void* d_out, int out_size, void* d_ws, size_t ws_size,
                              hipStream_t stream) {
    const float* x    = (const float*)d_in[0];
    const float* Wenc = (const float*)d_in[1];
    const float* benc = (const float*)d_in[2];
    const float* Wdec = (const float*)d_in[3];
    const float* bdec = (const float*)d_in[4];

    float* xhat = (float*)d_out;                        // [8192, 768]
    float* z    = (float*)d_out + (size_t)MB * KIN;     // [8192, 16384]

    const size_t szA  = (size_t)MB * KIN * 2;           // 12.58 MB
    const size_t szB  = (size_t)NSAE * KIN * 2;         // 25.17 MB
    const size_t szWT = (size_t)NSAE * KIN * 4;         // 50.33 MB
    const size_t szWd = (size_t)NSAE * KIN * 2;         // 25.17 MB

    if (ws_size >= szA + szB + szWT + szWd) {
        unsigned short* Aws = (unsigned short*)d_ws;
        unsigned short* Bws = (unsigned short*)((char*)d_ws + szA);
        float*          WT  = (float*)((char*)d_ws + szA + szB);
        unsigned short* WdB = (unsigned short*)((char*)d_ws + szA + szB + szWT);
        unsigned short* preB = (unsigned short*)z;      // row-strided bf16 pre
        conv_x<<<dim3(MB * (KIN / 8) / 256), dim3(256), 0, stream>>>(x, bdec, Aws);
        transpose_wenc<<<dim3(NSAE / 32, KIN / 32), dim3(256), 0, stream>>>(Wenc, WT, Bws);
        conv_wdec<<<dim3((NSAE / 8) * (KIN / 256)), dim3(256), 0, stream>>>(Wdec, WdB);
        sae_encode_mfma<<<dim3(MB / 256, NSAE / 128), dim3(512), 0, stream>>>(
            Aws, Bws, benc, preB, NSAE * 2);
        sae_fused<<<dim3(MB), dim3(256), 0, stream>>>(
            x, WT, benc, bdec, WdB, xhat, z);
    } else if (ws_size >= szWT) {
        float* WT = (float*)d_ws;
        sae_encode_gemm<<<dim3(NSAE / BN, MB / BM), dim3(256), 0, stream>>>(
            x, Wenc, benc, bdec, z);
        transpose_wenc<<<dim3(NSAE / 32, KIN / 32), dim3(256), 0, stream>>>(Wenc, WT, nullptr);
        sae_topk_decode<true><<<dim3(MB), dim3(256), 0, stream>>>(
            z, x, WT, benc, Wdec, bdec, xhat);
    } else {
        sae_encode_gemm<<<dim3(NSAE / BN, MB / BM), dim3(256), 0, stream>>>(
            x, Wenc, benc, bdec, z);
        sae_topk_decode<false><<<dim3(MB), dim3(256), 0, stream>>>(
            z, x, Wenc, benc, Wdec, bdec, xhat);
    }
}